// Round 13
// baseline (892.544 us; speedup 1.0000x reference)
//
#include <hip/hip_runtime.h>
#include <hip/hip_bf16.h>

// Problem constants
#define BB 4
#define CC 256
#define TT 16
#define HW 196
#define DEMO_T 4
#define OBS_T 12
#define DPOS 784      // DEMO_T*HW
#define OPOS 2352     // OBS_T*HW
#define XROW 3136     // TT*HW
#define NHEADS 8
#define CH 32
#define NPOS 980      // DPOS + HW (cat keys per (b,t,n))

typedef float  f32x4 __attribute__((ext_vector_type(4)));
typedef short  s8v   __attribute__((ext_vector_type(8)));
typedef short  s4v   __attribute__((ext_vector_type(4)));

// bf16 convert via official cast — compiler fuses pairs into v_cvt_pk_bf16_f32
static __device__ __forceinline__ ushort f2bf(float f) {
    union { __hip_bfloat16 h; ushort u; } cv;
    cv.h = __float2bfloat16(f);
    return cv.u;
}
static __device__ __forceinline__ short bfr(float f) { return (short)f2bf(f); }

static __device__ __forceinline__ float fast_rcp(float x) {
#if __has_builtin(__builtin_amdgcn_rcpf)
    return __builtin_amdgcn_rcpf(x);
#else
    return 1.f / x;
#endif
}

static __device__ __forceinline__ float fexp2(float x) {
#if __has_builtin(__builtin_amdgcn_exp2f)
    return __builtin_amdgcn_exp2f(x);
#else
    return exp2f(x);
#endif
}

// DPP row-rotate add: allreduce-sum across an aligned 16-lane row in 4 VALU
// ops. CTRL: 0x120|n = row_ror:n.
template<int CTRL>
static __device__ __forceinline__ float dpp_add(float x) {
    union { float f; int i; } a, o;
    a.f = x;
    o.i = __builtin_amdgcn_update_dpp(0, a.i, CTRL, 0xF, 0xF, true);
    return x + o.f;
}
static __device__ __forceinline__ float row16_sum(float x) {
    x = dpp_add<0x128>(x);   // ror 8
    x = dpp_add<0x124>(x);   // ror 4
    x = dpp_add<0x122>(x);   // ror 2
    x = dpp_add<0x121>(x);   // ror 1
    return x;
}

static __device__ __forceinline__ f32x4 mfma_pv(s4v a, s4v b, f32x4 c) {
#if __has_builtin(__builtin_amdgcn_mfma_f32_16x16x16bf16_1k)
    return __builtin_amdgcn_mfma_f32_16x16x16bf16_1k(a, b, c, 0, 0, 0);
#else
    s8v a8 = {a[0], a[1], a[2], a[3], 0, 0, 0, 0};
    s8v b8 = {b[0], b[1], b[2], b[3], 0, 0, 0, 0};
    return __builtin_amdgcn_mfma_f32_16x16x32_bf16(a8, b8, c, 0, 0, 0);
#endif
}

// ---------------------------------------------------------------------------
// pack_T: fp32 [b][256][P] -> bf16 [b][8][P][32]  (per-c-chunk transpose)
// ---------------------------------------------------------------------------
__global__ __launch_bounds__(256) void pack_T(
    const float* __restrict__ src, ushort* __restrict__ dst, int P)
{
    const int hn = blockIdx.y, bb = blockIdx.z;
    const int p0 = blockIdx.x * 64;
    __shared__ float L[32][73];
    const int tid = threadIdx.x;
    {
        const int c = tid >> 3, sg = tid & 7;
        const int p = p0 + sg*8;
        const float* s = src + ((size_t)bb*CC + hn*CH + c) * P + p;
        float4 a = {0,0,0,0}, b2 = {0,0,0,0};
        if (p < P) { a = *reinterpret_cast<const float4*>(s);
                     b2 = *reinterpret_cast<const float4*>(s + 4); }
        L[c][sg*8+0]=a.x;  L[c][sg*8+1]=a.y;  L[c][sg*8+2]=a.z;  L[c][sg*8+3]=a.w;
        L[c][sg*8+4]=b2.x; L[c][sg*8+5]=b2.y; L[c][sg*8+6]=b2.z; L[c][sg*8+7]=b2.w;
    }
    __syncthreads();
    {
        const int pl = tid >> 2, cs = (tid & 3) * 8;
        if (p0 + pl < P) {
            ushort o[8];
            #pragma unroll
            for (int j = 0; j < 8; j++) o[j] = f2bf(L[cs+j][pl]);
            uint4 v;
            v.x = o[0] | ((uint)o[1]<<16); v.y = o[2] | ((uint)o[3]<<16);
            v.z = o[4] | ((uint)o[5]<<16); v.w = o[6] | ((uint)o[7]<<16);
            *reinterpret_cast<uint4*>(dst + (((size_t)bb*NHEADS + hn)*P + p0 + pl)*32 + cs) = v;
        }
    }
}

// ---------------------------------------------------------------------------
// pack_w7: all 7 weight tensors fp32 -> bf16 in ONE launch (y selects pair)
// ---------------------------------------------------------------------------
__global__ __launch_bounds__(256) void pack_w7(
    const float* __restrict__ s0, const float* __restrict__ s1,
    const float* __restrict__ s2, const float* __restrict__ s3,
    const float* __restrict__ s4, const float* __restrict__ s5,
    const float* __restrict__ s6,
    ushort* __restrict__ d0, ushort* __restrict__ d1, ushort* __restrict__ d2,
    ushort* __restrict__ d3, ushort* __restrict__ d4, ushort* __restrict__ d5,
    ushort* __restrict__ d6, int n4)
{
    const float* src; ushort* dst;
    switch (blockIdx.y) {
        case 0: src = s0; dst = d0; break;
        case 1: src = s1; dst = d1; break;
        case 2: src = s2; dst = d2; break;
        case 3: src = s3; dst = d3; break;
        case 4: src = s4; dst = d4; break;
        case 5: src = s5; dst = d5; break;
        default: src = s6; dst = d6; break;
    }
    for (size_t i = (size_t)blockIdx.x * 256 + threadIdx.x; i < (size_t)n4;
         i += (size_t)gridDim.x * 256) {
        const float4 v = *reinterpret_cast<const float4*>(src + i*4);
        uint2 o;
        o.x = f2bf(v.x) | ((uint)f2bf(v.y) << 16);
        o.y = f2bf(v.z) | ((uint)f2bf(v.w) << 16);
        *reinterpret_cast<uint2*>(dst + i*4) = o;
    }
}

// ---------------------------------------------------------------------------
// bf16 MFMA projection GEMM with fused pack epilogues (+ per-z output scale).
//   variant 0 = packed-T bf16 [b][8][OP][32]; 1 = natural bf16 [b][256][OP];
//   2 = natural fp32 [b][256][OP]
// XPK2 (optional): second B-source summed with the first (K=512, same W) —
// folds the obs-attention p-split partial add into the out-projection.
// ---------------------------------------------------------------------------
__global__ __launch_bounds__(256) void proj_mfma(
    const ushort* __restrict__ XPK, const ushort* __restrict__ XPK2,
    int P, int pOff, int ncols, int OP,
    const ushort* __restrict__ W0, const ushort* __restrict__ W1, const ushort* __restrict__ W2,
    void* __restrict__ O0, void* __restrict__ O1, void* __restrict__ O2,
    int v0, int v1, int v2, float sc0, float sc1, float sc2)
{
    const int ptiles = (ncols + 63) >> 6;
    const int b  = blockIdx.x / ptiles;
    const int pt = blockIdx.x % ptiles;
    const int fbase = blockIdx.y * 64;
    const int z = blockIdx.z;
    const ushort* W = (z == 0) ? W0 : (z == 1) ? W1 : W2;
    void*        O = (z == 0) ? O0 : (z == 1) ? O1 : O2;
    const int variant = (z == 0) ? v0 : (z == 1) ? v1 : v2;
    const float sc    = (z == 0) ? sc0 : (z == 1) ? sc1 : sc2;

    const int tid = threadIdx.x, lane = tid & 63, w = tid >> 6;
    const int l15 = lane & 15, grp = lane >> 4;

    __shared__ float Cf[64][68];

    f32x4 acc[4];
    #pragma unroll
    for (int nt = 0; nt < 4; ++nt) acc[nt] = (f32x4){0.f, 0.f, 0.f, 0.f};

    const ushort* Wrow = W + (size_t)(fbase + w*16 + l15) * CC;
    int prow[4];
    #pragma unroll
    for (int nt = 0; nt < 4; ++nt) {
        const int p = pt*64 + nt*16 + l15;
        prow[nt] = (p < ncols) ? p : (ncols - 1);   // clamp: dup rows discarded
    }
    const size_t xb = (size_t)b * 8;

    #pragma unroll
    for (int kc = 0; kc < 8; ++kc) {
        const s8v aW = *reinterpret_cast<const s8v*>(Wrow + kc*32 + grp*8);
        #pragma unroll
        for (int nt = 0; nt < 4; ++nt) {
            const s8v bX = *reinterpret_cast<const s8v*>(
                XPK + ((xb + kc)*P + pOff + prow[nt])*32 + grp*8);
            acc[nt] = __builtin_amdgcn_mfma_f32_16x16x32_bf16(aW, bX, acc[nt], 0, 0, 0);
        }
    }
    if (XPK2) {
        #pragma unroll
        for (int kc = 0; kc < 8; ++kc) {
            const s8v aW = *reinterpret_cast<const s8v*>(Wrow + kc*32 + grp*8);
            #pragma unroll
            for (int nt = 0; nt < 4; ++nt) {
                const s8v bX = *reinterpret_cast<const s8v*>(
                    XPK2 + ((xb + kc)*P + pOff + prow[nt])*32 + grp*8);
                acc[nt] = __builtin_amdgcn_mfma_f32_16x16x32_bf16(aW, bX, acc[nt], 0, 0, 0);
            }
        }
    }
    #pragma unroll
    for (int nt = 0; nt < 4; ++nt)
        #pragma unroll
        for (int r = 0; r < 4; ++r)
            Cf[w*16 + grp*4 + r][nt*16 + l15] = acc[nt][r] * sc;
    __syncthreads();

    if (variant == 0) {
        ushort* dst = (ushort*)O;
        const int p_l = tid >> 2, c8 = (tid & 3) * 8;
        const int opos = pt*64 + p_l;
        if (opos < ncols) {
            #pragma unroll
            for (int hq = 0; hq < 2; ++hq) {
                ushort e[8];
                #pragma unroll
                for (int j = 0; j < 8; ++j) e[j] = f2bf(Cf[hq*32 + c8 + j][p_l]);
                uint4 v;
                v.x = e[0] | ((uint)e[1]<<16); v.y = e[2] | ((uint)e[3]<<16);
                v.z = e[4] | ((uint)e[5]<<16); v.w = e[6] | ((uint)e[7]<<16);
                *reinterpret_cast<uint4*>(
                    dst + (((size_t)b*NHEADS + (fbase >> 5) + hq)*OP + opos)*32 + c8) = v;
            }
        }
    } else if (variant == 1) {
        ushort* dst = (ushort*)O;
        #pragma unroll
        for (int pass = 0; pass < 2; ++pass) {
            const int idx = pass*256 + tid;
            const int f_l = idx >> 3, u = idx & 7;
            const int p0 = pt*64 + u*8;
            if (p0 < ncols) {
                ushort e[8];
                #pragma unroll
                for (int j = 0; j < 8; ++j) e[j] = f2bf(Cf[f_l][u*8 + j]);
                uint4 v;
                v.x = e[0] | ((uint)e[1]<<16); v.y = e[2] | ((uint)e[3]<<16);
                v.z = e[4] | ((uint)e[5]<<16); v.w = e[6] | ((uint)e[7]<<16);
                *reinterpret_cast<uint4*>(
                    dst + ((size_t)b*CC + fbase + f_l)*OP + p0) = v;
            }
        }
    } else {
        float* dst = (float*)O;
        #pragma unroll
        for (int pass = 0; pass < 2; ++pass) {
            const int idx = pass*256 + tid;
            const int f_l = idx >> 3, u = idx & 7;
            const int p0 = pt*64 + u*8;
            if (p0 < ncols) {
                float* dp = dst + ((size_t)b*CC + fbase + f_l)*OP + p0;
                *reinterpret_cast<float4*>(dp)     = *reinterpret_cast<const float4*>(&Cf[f_l][u*8]);
                *reinterpret_cast<float4*>(dp + 4) = *reinterpret_cast<const float4*>(&Cf[f_l][u*8 + 4]);
            }
        }
    }
}

// ---------------------------------------------------------------------------
// Demo attention — bf16 MFMA, 512 threads, NO-MAX softmax, barrier-free main
// loop. Q pre-scaled by log2(e)/16 at pack time -> raw exp2 here.
// ---------------------------------------------------------------------------
__global__ __launch_bounds__(512) void demo_attn_mfma(
    const ushort* __restrict__ QdP, const ushort* __restrict__ KdP,
    const ushort* __restrict__ VdP, ushort* __restrict__ dvattP)
{
    const int ib = blockIdx.x, hn = blockIdx.y, bb = blockIdx.z;
    const int tid = threadIdx.x;
    const int g   = tid >> 8;          // j-half
    const int gt  = tid & 255;
    const int lane = tid & 63;
    const int w    = (tid >> 6) & 3;   // i-quarter
    const int l15 = lane & 15, grp = lane >> 4;

    __shared__ float mrg[2304];                       // Lb[256] Ob[2048]
    __shared__ __align__(16) ushort OutS[32*72];

    const size_t hBase = ((size_t)bb*NHEADS + hn) * DPOS;
    const size_t vRow0 = ((size_t)bb*CC + hn*CH) * DPOS;

    const int i_glob = ib*64 + w*16 + l15;
    const s8v bK = *reinterpret_cast<const s8v*>(KdP + (hBase + i_glob)*32 + grp*8);

    f32x4 accO[2] = {{0.f,0.f,0.f,0.f}, {0.f,0.f,0.f,0.f}};
    float l_run = 0.f;

    const int chFirst = g ? 7 : 0;
    const int chEnd   = g ? 13 : 7;
    for (int ch = chFirst; ch < chEnd; ++ch) {
        const int nt = (ch == 12) ? 1 : 4;
        for (int jt = 0; jt < nt; ++jt) {
            const s8v aQ = *reinterpret_cast<const s8v*>(
                QdP + (hBase + ch*64 + jt*16 + l15)*32 + grp*8);
            const f32x4 z = {0.f,0.f,0.f,0.f};
            const f32x4 st = __builtin_amdgcn_mfma_f32_16x16x32_bf16(aQ, bK, z, 0, 0, 0);
            const float e0 = fexp2(st[0]), e1 = fexp2(st[1]);
            const float e2 = fexp2(st[2]), e3 = fexp2(st[3]);
            l_run += (e0 + e1) + (e2 + e3);
            s4v pf4;
            pf4[0] = bfr(e0); pf4[1] = bfr(e1); pf4[2] = bfr(e2); pf4[3] = bfr(e3);
            #pragma unroll
            for (int ct = 0; ct < 2; ++ct) {
                const s4v aV = *reinterpret_cast<const s4v*>(
                    VdP + vRow0 + (size_t)(ct*16 + l15)*DPOS + ch*64 + jt*16 + grp*4);
                accO[ct] = mfma_pv(aV, pf4, accO[ct]);
            }
        }
    }
    // cross-grp partial-l reduce (j spans grp via the C-row mapping)
    l_run += __shfl_xor(l_run, 16);
    l_run += __shfl_xor(l_run, 32);

    // ---- merge: simple (l, O) add across groups, then normalize ----
    float* Lb = mrg;          // [256]
    float* Ob = mrg + 256;    // [256][8]
    if (g == 1) {
        Lb[w*64 + lane] = l_run;
        #pragma unroll
        for (int ct = 0; ct < 2; ++ct)
            #pragma unroll
            for (int r = 0; r < 4; ++r)
                Ob[(w*64 + lane)*8 + ct*4 + r] = accO[ct][r];
    }
    __syncthreads();
    if (g == 0) {
        const float linv = 1.f / (l_run + Lb[w*64 + lane]);
        #pragma unroll
        for (int ct = 0; ct < 2; ++ct)
            #pragma unroll
            for (int r = 0; r < 4; ++r) {
                const float o = (accO[ct][r] + Ob[(w*64 + lane)*8 + ct*4 + r]) * linv;
                OutS[(ct*16 + grp*4 + r)*72 + w*16 + l15] = f2bf(o);
            }
    }
    __syncthreads();
    if (g == 0) {
        const int c = gt >> 3, sg = gt & 7;
        const int col = ib*64 + sg*8;
        if (col < DPOS) {
            const uint4 v = *reinterpret_cast<const uint4*>(&OutS[c*72 + sg*8]);
            *reinterpret_cast<uint4*>(dvattP + vRow0 + (size_t)c*DPOS + col) = v;
        }
    }
}

// ---------------------------------------------------------------------------
// Obs attention — bf16 MFMA, 256 threads (4 waves), p-split grid, with
// __launch_bounds__(256, 4): min 4 waves/EU pins VGPR <= 128 (round 12
// compiled at 152, crossing the 128 occupancy cliff -> 2 blocks/CU and a
// 1.5-round dispatch; the cap restores 4 blocks/CU capacity so 768 blocks
// fill at 3/CU with smoothing slack). Block (tt, ph) owns p in [ph*512,
// +512), wave w owns 128 p (8 prefetched steps). Partial O (bf16 packed-T)
// -> mergedP0/mergedP1; out-projection sums them (K=512 dual-source).
// NO-MAX softmax, DPP row16 allreduce, Q pre-scaled log2(e)/16 -> exp2.
// ---------------------------------------------------------------------------
__global__ __launch_bounds__(256, 4) void obs_attn_mfma(
    const ushort* __restrict__ KdP, const ushort* __restrict__ KoP,
    const ushort* __restrict__ QP,  const ushort* __restrict__ VdP,
    const ushort* __restrict__ VoP,
    ushort* __restrict__ mergedP0, ushort* __restrict__ mergedP1)
{
    const int tt = blockIdx.x >> 1, ph = blockIdx.x & 1;
    const int hn = blockIdx.y, bb = blockIdx.z;
    __shared__ __align__(16) ushort smem_u[13568];   // QT[208][40] ∪ Ored[32][212]f32
    ushort* QT = smem_u;

    const int tid  = threadIdx.x;
    const int lane = tid & 63;
    const int w    = tid >> 6;          // 4 waves
    const int l15  = lane & 15, grp = lane >> 4;

    const size_t kdBase = ((size_t)bb*NHEADS + hn) * DPOS * 32;
    const size_t koBase = ((size_t)bb*NHEADS + hn) * OPOS * 32 + (size_t)tt*HW*32;
    const size_t vdRow0 = ((size_t)bb*CC + hn*CH) * DPOS;
    const size_t voRow0 = ((size_t)bb*CC + hn*CH) * OPOS + (size_t)tt*HW;

    auto loadK = [&](int p0) -> s8v {
        const int pk = p0 + l15;
        s8v v = {0,0,0,0,0,0,0,0};
        if (pk < NPOS) {
            const ushort* kp = (pk < DPOS)
                ? KdP + kdBase + (size_t)pk*32
                : KoP + koBase + (size_t)(pk - DPOS)*32;
            v = *reinterpret_cast<const s8v*>(kp + grp*8);
        }
        return v;
    };
    auto loadV = [&](int ct, int p0) -> s4v {
        const int c  = ct*16 + l15;
        const int pv = p0 + grp*4;
        s4v v = {0,0,0,0};
        if (pv < NPOS) {
            const ushort* vp = (pv < DPOS)
                ? VdP + vdRow0 + (size_t)c*DPOS + pv
                : VoP + voRow0 + (size_t)c*OPOS + (pv - DPOS);
            v = *reinterpret_cast<const s4v*>(vp);
        }
        return v;
    };

    // stage Q once (rows >= 196 zero)
    for (int idx = tid; idx < 832; idx += 256) {
        const int r = idx >> 2, sg = idx & 3;
        uint4 v = {0,0,0,0};
        if (r < HW) v = *reinterpret_cast<const uint4*>(QP + koBase + (size_t)r*32 + sg*8);
        *reinterpret_cast<uint4*>(&QT[r*40 + sg*8]) = v;
    }

    f32x4 accO[2][13];
    #pragma unroll
    for (int ct = 0; ct < 2; ++ct)
        #pragma unroll
        for (int qt = 0; qt < 13; ++qt)
            accO[ct][qt] = (f32x4){0.f, 0.f, 0.f, 0.f};

    const int pw = ph*512 + w*128;
    s8v curK  = loadK(pw);
    s4v curV0 = loadV(0, pw);
    s4v curV1 = loadV(1, pw);
    __syncthreads();

    for (int s = 0; s < 8; ++s) {
        // ---- prefetch next step's K/V (off the critical path) ----
        s8v nK = {0,0,0,0,0,0,0,0};
        s4v nV0 = {0,0,0,0}, nV1 = {0,0,0,0};
        if (s < 7) {
            const int np = pw + (s+1)*16;
            nK  = loadK(np);
            nV0 = loadV(0, np);
            nV1 = loadV(1, np);
        }
        // ---- S: 13 q-tiles ----
        f32x4 ss[13];
        #pragma unroll
        for (int qt = 0; qt < 13; ++qt) {
            const s8v bQ = *reinterpret_cast<const s8v*>(&QT[(qt*16 + l15)*40 + grp*8]);
            const f32x4 z = {0.f, 0.f, 0.f, 0.f};
            ss[qt] = __builtin_amdgcn_mfma_f32_16x16x32_bf16(curK, bQ, z, 0, 0, 0);
        }
        // ---- no-max softmax over q per p-row (DPP row16 allreduce) ----
        #pragma unroll
        for (int r = 0; r < 4; ++r) {
            #pragma unroll
            for (int qt = 0; qt < 13; ++qt) ss[qt][r] = fexp2(ss[qt][r]);
            if (l15 >= 4) ss[12][r] = 0.f;   // q >= 196 pad
            float sum = ((((ss[0][r]+ss[1][r]) + (ss[2][r]+ss[3][r]))
                        + ((ss[4][r]+ss[5][r]) + (ss[6][r]+ss[7][r])))
                        + (((ss[8][r]+ss[9][r]) + (ss[10][r]+ss[11][r])) + ss[12][r]));
            sum = row16_sum(sum);
            const float is = fast_rcp(sum);
            #pragma unroll
            for (int qt = 0; qt < 13; ++qt) ss[qt][r] *= is;
        }
        s4v pf[13];
        #pragma unroll
        for (int qt = 0; qt < 13; ++qt) {
            s4v p4;
            #pragma unroll
            for (int r = 0; r < 4; ++r) p4[r] = bfr(ss[qt][r]);
            pf[qt] = p4;
        }
        // ---- PV with current V fragments ----
        #pragma unroll
        for (int qt = 0; qt < 13; ++qt)
            accO[0][qt] = mfma_pv(curV0, pf[qt], accO[0][qt]);
        #pragma unroll
        for (int qt = 0; qt < 13; ++qt)
            accO[1][qt] = mfma_pv(curV1, pf[qt], accO[1][qt]);

        curK = nK; curV0 = nV0; curV1 = nV1;
    }
    __syncthreads();

    // ---- 4-round wave reduction into Ored ----
    float* Og = reinterpret_cast<float*>(smem_u);   // [32][212]
    for (int wv = 0; wv < 4; ++wv) {
        if (w == wv) {
            #pragma unroll
            for (int ct = 0; ct < 2; ++ct)
                #pragma unroll
                for (int qt = 0; qt < 13; ++qt)
                    #pragma unroll
                    for (int r = 0; r < 4; ++r) {
                        const int c = ct*16 + grp*4 + r;
                        const int q = qt*16 + l15;
                        if (wv == 0) Og[c*212 + q]  = accO[ct][qt][r];
                        else         Og[c*212 + q] += accO[ct][qt][r];
                    }
        }
        __syncthreads();
    }
    // convert, store packed-T bf16 partial [q][32c]
    ushort* mp = ph ? mergedP1 : mergedP0;
    for (int idx = tid; idx < HW*4; idx += 256) {
        const int q = idx >> 2, c8 = (idx & 3) * 8;
        ushort e[8];
        #pragma unroll
        for (int j = 0; j < 8; ++j) e[j] = f2bf(Og[(c8 + j)*212 + q]);
        uint4 v;
        v.x = e[0] | ((uint)e[1]<<16); v.y = e[2] | ((uint)e[3]<<16);
        v.z = e[4] | ((uint)e[5]<<16); v.w = e[6] | ((uint)e[7]<<16);
        *reinterpret_cast<uint4*>(
            mp + (((size_t)bb*NHEADS + hn)*OPOS + (size_t)tt*HW + q)*32 + c8) = v;
    }
}

// ---------------------------------------------------------------------------
// Fused residual-ReLU + concat + BatchNorm. One block per channel. float4.
// ---------------------------------------------------------------------------
__global__ __launch_bounds__(256) void bn_fuse(
    const float* __restrict__ xin, const float* __restrict__ obsout,
    const float* __restrict__ gamma, const float* __restrict__ beta,
    float* __restrict__ xout)
{
    const int c = blockIdx.x;
    const int tid = threadIdx.x;
    float sum = 0.f, sumsq = 0.f;
    for (int idx = tid; idx < BB*(DPOS/4); idx += 256) {
        const int b = idx / (DPOS/4), pos = idx % (DPOS/4);
        const float4 v = *reinterpret_cast<const float4*>(
            &xin[((size_t)b*CC + c) * XROW + pos*4]);
        sum   += v.x + v.y + v.z + v.w;
        sumsq += v.x*v.x + v.y*v.y + v.z*v.z + v.w*v.w;
    }
    for (int idx = tid; idx < BB*(OPOS/4); idx += 256) {
        const int b = idx / (OPOS/4), pos = idx % (OPOS/4);
        const float4 xv = *reinterpret_cast<const float4*>(
            &xin[((size_t)b*CC + c) * XROW + DPOS + pos*4]);
        const float4 ov = *reinterpret_cast<const float4*>(
            &obsout[((size_t)b*CC + c) * OPOS + pos*4]);
        const float4 v = make_float4(xv.x + fmaxf(ov.x, 0.f), xv.y + fmaxf(ov.y, 0.f),
                                     xv.z + fmaxf(ov.z, 0.f), xv.w + fmaxf(ov.w, 0.f));
        sum   += v.x + v.y + v.z + v.w;
        sumsq += v.x*v.x + v.y*v.y + v.z*v.z + v.w*v.w;
    }
    #pragma unroll
    for (int off = 32; off > 0; off >>= 1) {
        sum   += __shfl_xor(sum, off);
        sumsq += __shfl_xor(sumsq, off);
    }
    __shared__ float ssum[4], ssq[4];
    __shared__ float s_mean, s_inv;
    const int lane = tid & 63, w = tid >> 6;
    if (lane == 0) { ssum[w] = sum; ssq[w] = sumsq; }
    __syncthreads();
    if (tid == 0) {
        float s  = ssum[0] + ssum[1] + ssum[2] + ssum[3];
        float sq = ssq[0] + ssq[1] + ssq[2] + ssq[3];
        const float mean = s / 12544.f;
        const float var  = sq / 12544.f - mean * mean;
        s_mean = mean;
        s_inv  = rsqrtf(var + 1e-5f);
    }
    __syncthreads();
    const float mean = s_mean;
    const float gi = gamma[c] * s_inv;
    const float bt = beta[c];
    for (int idx = tid; idx < BB*(DPOS/4); idx += 256) {
        const int b = idx / (DPOS/4), pos = idx % (DPOS/4);
        const size_t o = ((size_t)b*CC + c) * XROW + pos*4;
        const float4 v = *reinterpret_cast<const float4*>(&xin[o]);
        const float4 r = make_float4((v.x-mean)*gi+bt, (v.y-mean)*gi+bt,
                                     (v.z-mean)*gi+bt, (v.w-mean)*gi+bt);
        *reinterpret_cast<float4*>(&xout[o]) = r;
    }
    for (int idx = tid; idx < BB*(OPOS/4); idx += 256) {
        const int b = idx / (OPOS/4), pos = idx % (OPOS/4);
        const float4 xv = *reinterpret_cast<const float4*>(
            &xin[((size_t)b*CC + c) * XROW + DPOS + pos*4]);
        const float4 ov = *reinterpret_cast<const float4*>(
            &obsout[((size_t)b*CC + c) * OPOS + pos*4]);
        const float4 v = make_float4(xv.x + fmaxf(ov.x, 0.f), xv.y + fmaxf(ov.y, 0.f),
                                     xv.z + fmaxf(ov.z, 0.f), xv.w + fmaxf(ov.w, 0.f));
        const float4 r = make_float4((v.x-mean)*gi+bt, (v.y-mean)*gi+bt,
                                     (v.z-mean)*gi+bt, (v.w-mean)*gi+bt);
        *reinterpret_cast<float4*>(&xout[((size_t)b*CC + c) * XROW + DPOS + pos*4]) = r;
    }
}

// ---------------------------------------------------------------------------
extern "C" void kernel_launch(void* const* d_in, const int* in_sizes, int n_in,
                              void* d_out, int out_size, void* d_ws, size_t ws_size,
                              hipStream_t stream)
{
    const float* x   = (const float*)d_in[0];
    const float* dqw = (const float*)d_in[1];
    const float* dkw = (const float*)d_in[2];
    const float* dvw = (const float*)d_in[3];
    const float* oqw = (const float*)d_in[4];
    const float* okw = (const float*)d_in[5];
    const float* ovw = (const float*)d_in[6];
    const float* oow = (const float*)d_in[7];
    const float* gam = (const float*)d_in[8];
    const float* bet = (const float*)d_in[9];

    const size_t XN = (size_t)BB * CC * TT * HW;   // 3,211,264
    const size_t DN = (size_t)BB * CC * DPOS;      //   802,816
    const size_t ON = (size_t)BB * CC * OPOS;      // 2,408,448
    const size_t WN = (size_t)3 * CC * CC;         //   196,608

    float*  xb0      = (float*)d_ws;
    float*  xb1      = xb0 + XN;
    float*  obsout   = xb1 + XN;
    ushort* XP       = (ushort*)(obsout + ON);    // [b][8][3136][32]
    ushort* QdP      = XP + XN;
    ushort* KdP      = QdP + DN;
    ushort* VdemoP   = KdP + DN;
    ushort* dvattP   = VdemoP + DN;
    ushort* QP       = dvattP + DN;
    ushort* KoP      = QP + ON;
    ushort* VoP      = KoP + ON;
    ushort* mergedP0 = VoP + ON;
    ushort* mergedP1 = mergedP0 + ON;
    ushort* wpk      = mergedP1 + ON;
    ushort* dqwb = wpk;          ushort* dkwb = wpk + WN;   ushort* dvwb = wpk + 2*WN;
    ushort* oqwb = wpk + 3*WN;   ushort* okwb = wpk + 4*WN; ushort* ovwb = wpk + 5*WN;
    ushort* oowb = wpk + 6*WN;

    const dim3 blk(256);
    const dim3 blk2(512);
    const float QS = 0.0625f * 1.44269504f;   // (1/sqrt(C)) * log2(e) -> raw exp2 in attn

    // all 7 weight packs in one launch
    pack_w7<<<dim3(192, 7), blk, 0, stream>>>(
        dqw, dkw, dvw, oqw, okw, ovw, oow,
        dqwb, dkwb, dvwb, oqwb, okwb, ovwb, oowb, (int)(WN/4));

    for (int i = 0; i < 3; i++) {
        const float* xin  = (i == 0) ? x : (i == 1 ? xb0 : xb1);
        float*       xout = (i == 2) ? (float*)d_out : (i == 0 ? xb0 : xb1);
        const size_t wB = (size_t)i * CC * CC;

        // 1: pack x -> XP
        pack_T<<<dim3(49, 8, BB), blk, 0, stream>>>(xin, XP, XROW);

        // 2: demo projections (Q scaled by log2(e)/16 at pack)
        proj_mfma<<<dim3(BB*13, 4, 3), blk, 0, stream>>>(
            XP, nullptr, XROW, 0, DPOS, DPOS,
            dqwb + wB, dkwb + wB, dvwb + wB,
            QdP, KdP, VdemoP, 0, 0, 1, QS, 1.f, 1.f);

        // 3: demo attention
        demo_attn_mfma<<<dim3(13, NHEADS, BB), blk2, 0, stream>>>(
            QdP, KdP, VdemoP, dvattP);

        // 4: obs projections (Q scaled by log2(e)/16 at pack)
        proj_mfma<<<dim3(BB*37, 4, 3), blk, 0, stream>>>(
            XP, nullptr, XROW, DPOS, OPOS, OPOS,
            oqwb + wB, okwb + wB, ovwb + wB,
            QP, KoP, VoP, 0, 0, 1, QS, 1.f, 1.f);

        // 5: obs attention (p-split, 768 x 256-thread blocks, VGPR capped)
        obs_attn_mfma<<<dim3(OBS_T*2, NHEADS, BB), blk, 0, stream>>>(
            KdP, KoP, QP, dvattP, VoP, mergedP0, mergedP1);

        // 6: output projection (fp32 out, K=512 over the two partials)
        proj_mfma<<<dim3(BB*37, 4, 1), blk, 0, stream>>>(
            mergedP0, mergedP1, OPOS, 0, OPOS, OPOS,
            oowb + wB, oowb + wB, oowb + wB,
            obsout, obsout, obsout, 2, 2, 2, 1.f, 1.f, 1.f);

        // 7: residual + BN
        bn_fuse<<<dim3(CC), blk, 0, stream>>>(xin, obsout, gam + i*CC, bet + i*CC, xout);
    }
}

// Round 14
// 391.044 us; speedup vs baseline: 2.2825x; 2.2825x over previous
//
#include <hip/hip_runtime.h>
#include <hip/hip_bf16.h>

// Problem constants
#define BB 4
#define CC 256
#define TT 16
#define HW 196
#define DEMO_T 4
#define OBS_T 12
#define DPOS 784      // DEMO_T*HW
#define OPOS 2352     // OBS_T*HW
#define XROW 3136     // TT*HW
#define NHEADS 8
#define CH 32
#define NPOS 980      // DPOS + HW (cat keys per (b,t,n))

typedef float  f32x4 __attribute__((ext_vector_type(4)));
typedef short  s8v   __attribute__((ext_vector_type(8)));
typedef short  s4v   __attribute__((ext_vector_type(4)));

// bf16 convert via official cast — compiler fuses pairs into v_cvt_pk_bf16_f32
static __device__ __forceinline__ ushort f2bf(float f) {
    union { __hip_bfloat16 h; ushort u; } cv;
    cv.h = __float2bfloat16(f);
    return cv.u;
}
static __device__ __forceinline__ short bfr(float f) { return (short)f2bf(f); }

static __device__ __forceinline__ float fast_rcp(float x) {
#if __has_builtin(__builtin_amdgcn_rcpf)
    return __builtin_amdgcn_rcpf(x);
#else
    return 1.f / x;
#endif
}

static __device__ __forceinline__ float fexp2(float x) {
#if __has_builtin(__builtin_amdgcn_exp2f)
    return __builtin_amdgcn_exp2f(x);
#else
    return exp2f(x);
#endif
}

// DPP row-rotate add: allreduce-sum across an aligned 16-lane row in 4 VALU
// ops. CTRL: 0x120|n = row_ror:n.
template<int CTRL>
static __device__ __forceinline__ float dpp_add(float x) {
    union { float f; int i; } a, o;
    a.f = x;
    o.i = __builtin_amdgcn_update_dpp(0, a.i, CTRL, 0xF, 0xF, true);
    return x + o.f;
}
static __device__ __forceinline__ float row16_sum(float x) {
    x = dpp_add<0x128>(x);   // ror 8
    x = dpp_add<0x124>(x);   // ror 4
    x = dpp_add<0x122>(x);   // ror 2
    x = dpp_add<0x121>(x);   // ror 1
    return x;
}

static __device__ __forceinline__ f32x4 mfma_pv(s4v a, s4v b, f32x4 c) {
#if __has_builtin(__builtin_amdgcn_mfma_f32_16x16x16bf16_1k)
    return __builtin_amdgcn_mfma_f32_16x16x16bf16_1k(a, b, c, 0, 0, 0);
#else
    s8v a8 = {a[0], a[1], a[2], a[3], 0, 0, 0, 0};
    s8v b8 = {b[0], b[1], b[2], b[3], 0, 0, 0, 0};
    return __builtin_amdgcn_mfma_f32_16x16x32_bf16(a8, b8, c, 0, 0, 0);
#endif
}

// ---------------------------------------------------------------------------
// pack_T: fp32 [b][256][P] -> bf16 [b][8][P][32]  (per-c-chunk transpose)
// ---------------------------------------------------------------------------
__global__ __launch_bounds__(256) void pack_T(
    const float* __restrict__ src, ushort* __restrict__ dst, int P)
{
    const int hn = blockIdx.y, bb = blockIdx.z;
    const int p0 = blockIdx.x * 64;
    __shared__ float L[32][73];
    const int tid = threadIdx.x;
    {
        const int c = tid >> 3, sg = tid & 7;
        const int p = p0 + sg*8;
        const float* s = src + ((size_t)bb*CC + hn*CH + c) * P + p;
        float4 a = {0,0,0,0}, b2 = {0,0,0,0};
        if (p < P) { a = *reinterpret_cast<const float4*>(s);
                     b2 = *reinterpret_cast<const float4*>(s + 4); }
        L[c][sg*8+0]=a.x;  L[c][sg*8+1]=a.y;  L[c][sg*8+2]=a.z;  L[c][sg*8+3]=a.w;
        L[c][sg*8+4]=b2.x; L[c][sg*8+5]=b2.y; L[c][sg*8+6]=b2.z; L[c][sg*8+7]=b2.w;
    }
    __syncthreads();
    {
        const int pl = tid >> 2, cs = (tid & 3) * 8;
        if (p0 + pl < P) {
            ushort o[8];
            #pragma unroll
            for (int j = 0; j < 8; j++) o[j] = f2bf(L[cs+j][pl]);
            uint4 v;
            v.x = o[0] | ((uint)o[1]<<16); v.y = o[2] | ((uint)o[3]<<16);
            v.z = o[4] | ((uint)o[5]<<16); v.w = o[6] | ((uint)o[7]<<16);
            *reinterpret_cast<uint4*>(dst + (((size_t)bb*NHEADS + hn)*P + p0 + pl)*32 + cs) = v;
        }
    }
}

// ---------------------------------------------------------------------------
// pack_w7: all 7 weight tensors fp32 -> bf16 in ONE launch (y selects pair)
// ---------------------------------------------------------------------------
__global__ __launch_bounds__(256) void pack_w7(
    const float* __restrict__ s0, const float* __restrict__ s1,
    const float* __restrict__ s2, const float* __restrict__ s3,
    const float* __restrict__ s4, const float* __restrict__ s5,
    const float* __restrict__ s6,
    ushort* __restrict__ d0, ushort* __restrict__ d1, ushort* __restrict__ d2,
    ushort* __restrict__ d3, ushort* __restrict__ d4, ushort* __restrict__ d5,
    ushort* __restrict__ d6, int n4)
{
    const float* src; ushort* dst;
    switch (blockIdx.y) {
        case 0: src = s0; dst = d0; break;
        case 1: src = s1; dst = d1; break;
        case 2: src = s2; dst = d2; break;
        case 3: src = s3; dst = d3; break;
        case 4: src = s4; dst = d4; break;
        case 5: src = s5; dst = d5; break;
        default: src = s6; dst = d6; break;
    }
    for (size_t i = (size_t)blockIdx.x * 256 + threadIdx.x; i < (size_t)n4;
         i += (size_t)gridDim.x * 256) {
        const float4 v = *reinterpret_cast<const float4*>(src + i*4);
        uint2 o;
        o.x = f2bf(v.x) | ((uint)f2bf(v.y) << 16);
        o.y = f2bf(v.z) | ((uint)f2bf(v.w) << 16);
        *reinterpret_cast<uint2*>(dst + i*4) = o;
    }
}

// ---------------------------------------------------------------------------
// bf16 MFMA projection GEMM with fused pack epilogues (+ per-z output scale).
//   variant 0 = packed-T bf16 [b][8][OP][32]; 1 = natural bf16 [b][256][OP];
//   2 = natural fp32 [b][256][OP]
// ---------------------------------------------------------------------------
__global__ __launch_bounds__(256) void proj_mfma(
    const ushort* __restrict__ XPK, int P, int pOff, int ncols, int OP,
    const ushort* __restrict__ W0, const ushort* __restrict__ W1, const ushort* __restrict__ W2,
    void* __restrict__ O0, void* __restrict__ O1, void* __restrict__ O2,
    int v0, int v1, int v2, float sc0, float sc1, float sc2)
{
    const int ptiles = (ncols + 63) >> 6;
    const int b  = blockIdx.x / ptiles;
    const int pt = blockIdx.x % ptiles;
    const int fbase = blockIdx.y * 64;
    const int z = blockIdx.z;
    const ushort* W = (z == 0) ? W0 : (z == 1) ? W1 : W2;
    void*        O = (z == 0) ? O0 : (z == 1) ? O1 : O2;
    const int variant = (z == 0) ? v0 : (z == 1) ? v1 : v2;
    const float sc    = (z == 0) ? sc0 : (z == 1) ? sc1 : sc2;

    const int tid = threadIdx.x, lane = tid & 63, w = tid >> 6;
    const int l15 = lane & 15, grp = lane >> 4;

    __shared__ float Cf[64][68];

    f32x4 acc[4];
    #pragma unroll
    for (int nt = 0; nt < 4; ++nt) acc[nt] = (f32x4){0.f, 0.f, 0.f, 0.f};

    const ushort* Wrow = W + (size_t)(fbase + w*16 + l15) * CC;
    int prow[4];
    #pragma unroll
    for (int nt = 0; nt < 4; ++nt) {
        const int p = pt*64 + nt*16 + l15;
        prow[nt] = (p < ncols) ? p : (ncols - 1);   // clamp: dup rows discarded
    }
    const size_t xb = (size_t)b * 8;

    #pragma unroll
    for (int kc = 0; kc < 8; ++kc) {
        const s8v aW = *reinterpret_cast<const s8v*>(Wrow + kc*32 + grp*8);
        #pragma unroll
        for (int nt = 0; nt < 4; ++nt) {
            const s8v bX = *reinterpret_cast<const s8v*>(
                XPK + ((xb + kc)*P + pOff + prow[nt])*32 + grp*8);
            acc[nt] = __builtin_amdgcn_mfma_f32_16x16x32_bf16(aW, bX, acc[nt], 0, 0, 0);
        }
    }
    #pragma unroll
    for (int nt = 0; nt < 4; ++nt)
        #pragma unroll
        for (int r = 0; r < 4; ++r)
            Cf[w*16 + grp*4 + r][nt*16 + l15] = acc[nt][r] * sc;
    __syncthreads();

    if (variant == 0) {
        ushort* dst = (ushort*)O;
        const int p_l = tid >> 2, c8 = (tid & 3) * 8;
        const int opos = pt*64 + p_l;
        if (opos < ncols) {
            #pragma unroll
            for (int hq = 0; hq < 2; ++hq) {
                ushort e[8];
                #pragma unroll
                for (int j = 0; j < 8; ++j) e[j] = f2bf(Cf[hq*32 + c8 + j][p_l]);
                uint4 v;
                v.x = e[0] | ((uint)e[1]<<16); v.y = e[2] | ((uint)e[3]<<16);
                v.z = e[4] | ((uint)e[5]<<16); v.w = e[6] | ((uint)e[7]<<16);
                *reinterpret_cast<uint4*>(
                    dst + (((size_t)b*NHEADS + (fbase >> 5) + hq)*OP + opos)*32 + c8) = v;
            }
        }
    } else if (variant == 1) {
        ushort* dst = (ushort*)O;
        #pragma unroll
        for (int pass = 0; pass < 2; ++pass) {
            const int idx = pass*256 + tid;
            const int f_l = idx >> 3, u = idx & 7;
            const int p0 = pt*64 + u*8;
            if (p0 < ncols) {
                ushort e[8];
                #pragma unroll
                for (int j = 0; j < 8; ++j) e[j] = f2bf(Cf[f_l][u*8 + j]);
                uint4 v;
                v.x = e[0] | ((uint)e[1]<<16); v.y = e[2] | ((uint)e[3]<<16);
                v.z = e[4] | ((uint)e[5]<<16); v.w = e[6] | ((uint)e[7]<<16);
                *reinterpret_cast<uint4*>(
                    dst + ((size_t)b*CC + fbase + f_l)*OP + p0) = v;
            }
        }
    } else {
        float* dst = (float*)O;
        #pragma unroll
        for (int pass = 0; pass < 2; ++pass) {
            const int idx = pass*256 + tid;
            const int f_l = idx >> 3, u = idx & 7;
            const int p0 = pt*64 + u*8;
            if (p0 < ncols) {
                float* dp = dst + ((size_t)b*CC + fbase + f_l)*OP + p0;
                *reinterpret_cast<float4*>(dp)     = *reinterpret_cast<const float4*>(&Cf[f_l][u*8]);
                *reinterpret_cast<float4*>(dp + 4) = *reinterpret_cast<const float4*>(&Cf[f_l][u*8 + 4]);
            }
        }
    }
}

// ---------------------------------------------------------------------------
// Demo attention — bf16 MFMA, 512 threads, NO-MAX softmax, barrier-free main
// loop. Q pre-scaled by log2(e)/16 at pack time -> raw exp2 here.
// ---------------------------------------------------------------------------
__global__ __launch_bounds__(512) void demo_attn_mfma(
    const ushort* __restrict__ QdP, const ushort* __restrict__ KdP,
    const ushort* __restrict__ VdP, ushort* __restrict__ dvattP)
{
    const int ib = blockIdx.x, hn = blockIdx.y, bb = blockIdx.z;
    const int tid = threadIdx.x;
    const int g   = tid >> 8;          // j-half
    const int gt  = tid & 255;
    const int lane = tid & 63;
    const int w    = (tid >> 6) & 3;   // i-quarter
    const int l15 = lane & 15, grp = lane >> 4;

    __shared__ float mrg[2304];                       // Lb[256] Ob[2048]
    __shared__ __align__(16) ushort OutS[32*72];

    const size_t hBase = ((size_t)bb*NHEADS + hn) * DPOS;
    const size_t vRow0 = ((size_t)bb*CC + hn*CH) * DPOS;

    const int i_glob = ib*64 + w*16 + l15;
    const s8v bK = *reinterpret_cast<const s8v*>(KdP + (hBase + i_glob)*32 + grp*8);

    f32x4 accO[2] = {{0.f,0.f,0.f,0.f}, {0.f,0.f,0.f,0.f}};
    float l_run = 0.f;

    const int chFirst = g ? 7 : 0;
    const int chEnd   = g ? 13 : 7;
    for (int ch = chFirst; ch < chEnd; ++ch) {
        const int nt = (ch == 12) ? 1 : 4;
        for (int jt = 0; jt < nt; ++jt) {
            const s8v aQ = *reinterpret_cast<const s8v*>(
                QdP + (hBase + ch*64 + jt*16 + l15)*32 + grp*8);
            const f32x4 z = {0.f,0.f,0.f,0.f};
            const f32x4 st = __builtin_amdgcn_mfma_f32_16x16x32_bf16(aQ, bK, z, 0, 0, 0);
            const float e0 = fexp2(st[0]), e1 = fexp2(st[1]);
            const float e2 = fexp2(st[2]), e3 = fexp2(st[3]);
            l_run += (e0 + e1) + (e2 + e3);
            s4v pf4;
            pf4[0] = bfr(e0); pf4[1] = bfr(e1); pf4[2] = bfr(e2); pf4[3] = bfr(e3);
            #pragma unroll
            for (int ct = 0; ct < 2; ++ct) {
                const s4v aV = *reinterpret_cast<const s4v*>(
                    VdP + vRow0 + (size_t)(ct*16 + l15)*DPOS + ch*64 + jt*16 + grp*4);
                accO[ct] = mfma_pv(aV, pf4, accO[ct]);
            }
        }
    }
    // cross-grp partial-l reduce (j spans grp via the C-row mapping)
    l_run += __shfl_xor(l_run, 16);
    l_run += __shfl_xor(l_run, 32);

    // ---- merge: simple (l, O) add across groups, then normalize ----
    float* Lb = mrg;          // [256]
    float* Ob = mrg + 256;    // [256][8]
    if (g == 1) {
        Lb[w*64 + lane] = l_run;
        #pragma unroll
        for (int ct = 0; ct < 2; ++ct)
            #pragma unroll
            for (int r = 0; r < 4; ++r)
                Ob[(w*64 + lane)*8 + ct*4 + r] = accO[ct][r];
    }
    __syncthreads();
    if (g == 0) {
        const float linv = 1.f / (l_run + Lb[w*64 + lane]);
        #pragma unroll
        for (int ct = 0; ct < 2; ++ct)
            #pragma unroll
            for (int r = 0; r < 4; ++r) {
                const float o = (accO[ct][r] + Ob[(w*64 + lane)*8 + ct*4 + r]) * linv;
                OutS[(ct*16 + grp*4 + r)*72 + w*16 + l15] = f2bf(o);
            }
    }
    __syncthreads();
    if (g == 0) {
        const int c = gt >> 3, sg = gt & 7;
        const int col = ib*64 + sg*8;
        if (col < DPOS) {
            const uint4 v = *reinterpret_cast<const uint4*>(&OutS[c*72 + sg*8]);
            *reinterpret_cast<uint4*>(dvattP + vRow0 + (size_t)c*DPOS + col) = v;
        }
    }
}

// ---------------------------------------------------------------------------
// Obs attention per (b, t, n) — bf16 MFMA, 512 threads, barrier-free main
// loop (round-11 structure) + register prefetch of next-step K/V fragments.
// NO-MAX softmax, DPP row16 allreduce, Q pre-scaled log2(e)/16 -> exp2.
// ---------------------------------------------------------------------------
__global__ __launch_bounds__(512) void obs_attn_mfma(
    const ushort* __restrict__ KdP, const ushort* __restrict__ KoP,
    const ushort* __restrict__ QP,  const ushort* __restrict__ VdP,
    const ushort* __restrict__ VoP, ushort* __restrict__ mergedP)
{
    const int tt = blockIdx.x, hn = blockIdx.y, bb = blockIdx.z;
    __shared__ __align__(16) ushort smem_u[27136];   // QT[208][40] ∪ Ored[2][32][212]f32
    ushort* QT = smem_u;

    const int tid  = threadIdx.x;
    const int g    = tid >> 8;
    const int lane = tid & 63;
    const int w    = (tid >> 6) & 3;
    const int l15  = lane & 15, grp = lane >> 4;

    const size_t kdBase = ((size_t)bb*NHEADS + hn) * DPOS * 32;
    const size_t koBase = ((size_t)bb*NHEADS + hn) * OPOS * 32 + (size_t)tt*HW*32;
    const size_t vdRow0 = ((size_t)bb*CC + hn*CH) * DPOS;
    const size_t voRow0 = ((size_t)bb*CC + hn*CH) * OPOS + (size_t)tt*HW;

    auto loadK = [&](int p0) -> s8v {
        const int pk = p0 + l15;
        s8v v = {0,0,0,0,0,0,0,0};
        if (pk < NPOS) {
            const ushort* kp = (pk < DPOS)
                ? KdP + kdBase + (size_t)pk*32
                : KoP + koBase + (size_t)(pk - DPOS)*32;
            v = *reinterpret_cast<const s8v*>(kp + grp*8);
        }
        return v;
    };
    auto loadV = [&](int ct, int p0) -> s4v {
        const int c  = ct*16 + l15;
        const int pv = p0 + grp*4;
        s4v v = {0,0,0,0};
        if (pv < NPOS) {
            const ushort* vp = (pv < DPOS)
                ? VdP + vdRow0 + (size_t)c*DPOS + pv
                : VoP + voRow0 + (size_t)c*OPOS + (pv - DPOS);
            v = *reinterpret_cast<const s4v*>(vp);
        }
        return v;
    };

    // stage Q once (rows >= 196 zero)
    for (int idx = tid; idx < 832; idx += 512) {
        const int r = idx >> 2, sg = idx & 3;
        uint4 v = {0,0,0,0};
        if (r < HW) v = *reinterpret_cast<const uint4*>(QP + koBase + (size_t)r*32 + sg*8);
        *reinterpret_cast<uint4*>(&QT[r*40 + sg*8]) = v;
    }

    f32x4 accO[2][13];
    #pragma unroll
    for (int ct = 0; ct < 2; ++ct)
        #pragma unroll
        for (int qt = 0; qt < 13; ++qt)
            accO[ct][qt] = (f32x4){0.f, 0.f, 0.f, 0.f};

    const int pw = (g*4 + w) * 128;
    s8v curK  = loadK(pw);
    s4v curV0 = loadV(0, pw);
    s4v curV1 = loadV(1, pw);
    __syncthreads();

    for (int s = 0; s < 8; ++s) {
        // ---- prefetch next step's K/V (off the critical path) ----
        s8v nK = {0,0,0,0,0,0,0,0};
        s4v nV0 = {0,0,0,0}, nV1 = {0,0,0,0};
        if (s < 7) {
            const int np = pw + (s+1)*16;
            nK  = loadK(np);
            nV0 = loadV(0, np);
            nV1 = loadV(1, np);
        }
        // ---- S: 13 q-tiles ----
        f32x4 ss[13];
        #pragma unroll
        for (int qt = 0; qt < 13; ++qt) {
            const s8v bQ = *reinterpret_cast<const s8v*>(&QT[(qt*16 + l15)*40 + grp*8]);
            const f32x4 z = {0.f, 0.f, 0.f, 0.f};
            ss[qt] = __builtin_amdgcn_mfma_f32_16x16x32_bf16(curK, bQ, z, 0, 0, 0);
        }
        // ---- no-max softmax over q per p-row (DPP row16 allreduce) ----
        #pragma unroll
        for (int r = 0; r < 4; ++r) {
            #pragma unroll
            for (int qt = 0; qt < 13; ++qt) ss[qt][r] = fexp2(ss[qt][r]);
            if (l15 >= 4) ss[12][r] = 0.f;   // q >= 196 pad
            float sum = ((((ss[0][r]+ss[1][r]) + (ss[2][r]+ss[3][r]))
                        + ((ss[4][r]+ss[5][r]) + (ss[6][r]+ss[7][r])))
                        + (((ss[8][r]+ss[9][r]) + (ss[10][r]+ss[11][r])) + ss[12][r]));
            sum = row16_sum(sum);
            const float is = fast_rcp(sum);
            #pragma unroll
            for (int qt = 0; qt < 13; ++qt) ss[qt][r] *= is;
        }
        s4v pf[13];
        #pragma unroll
        for (int qt = 0; qt < 13; ++qt) {
            s4v p4;
            #pragma unroll
            for (int r = 0; r < 4; ++r) p4[r] = bfr(ss[qt][r]);
            pf[qt] = p4;
        }
        // ---- PV with current V fragments ----
        #pragma unroll
        for (int qt = 0; qt < 13; ++qt)
            accO[0][qt] = mfma_pv(curV0, pf[qt], accO[0][qt]);
        #pragma unroll
        for (int qt = 0; qt < 13; ++qt)
            accO[1][qt] = mfma_pv(curV1, pf[qt], accO[1][qt]);

        curK = nK; curV0 = nV0; curV1 = nV1;
    }
    __syncthreads();

    // ---- per-group 4-wave reduction into Ored[g] ----
    float* OredF = reinterpret_cast<float*>(smem_u);   // [2][32][212]
    float* Og = OredF + g * 6784;
    for (int wv = 0; wv < 4; ++wv) {
        if (w == wv) {
            #pragma unroll
            for (int ct = 0; ct < 2; ++ct)
                #pragma unroll
                for (int qt = 0; qt < 13; ++qt)
                    #pragma unroll
                    for (int r = 0; r < 4; ++r) {
                        const int c = ct*16 + grp*4 + r;
                        const int q = qt*16 + l15;
                        if (wv == 0) Og[c*212 + q]  = accO[ct][qt][r];
                        else         Og[c*212 + q] += accO[ct][qt][r];
                    }
        }
        __syncthreads();
    }
    // add group partials, convert, store packed-T bf16 [q][32c]
    for (int idx = tid; idx < HW*4; idx += 512) {
        const int q = idx >> 2, c8 = (idx & 3) * 8;
        ushort e[8];
        #pragma unroll
        for (int j = 0; j < 8; ++j) {
            const int c = c8 + j;
            e[j] = f2bf(OredF[c*212 + q] + OredF[6784 + c*212 + q]);
        }
        uint4 v;
        v.x = e[0] | ((uint)e[1]<<16); v.y = e[2] | ((uint)e[3]<<16);
        v.z = e[4] | ((uint)e[5]<<16); v.w = e[6] | ((uint)e[7]<<16);
        *reinterpret_cast<uint4*>(
            mergedP + (((size_t)bb*NHEADS + hn)*OPOS + (size_t)tt*HW + q)*32 + c8) = v;
    }
}

// ---------------------------------------------------------------------------
// Fused residual-ReLU + concat + BatchNorm. One block per channel. float4.
// ---------------------------------------------------------------------------
__global__ __launch_bounds__(256) void bn_fuse(
    const float* __restrict__ xin, const float* __restrict__ obsout,
    const float* __restrict__ gamma, const float* __restrict__ beta,
    float* __restrict__ xout)
{
    const int c = blockIdx.x;
    const int tid = threadIdx.x;
    float sum = 0.f, sumsq = 0.f;
    for (int idx = tid; idx < BB*(DPOS/4); idx += 256) {
        const int b = idx / (DPOS/4), pos = idx % (DPOS/4);
        const float4 v = *reinterpret_cast<const float4*>(
            &xin[((size_t)b*CC + c) * XROW + pos*4]);
        sum   += v.x + v.y + v.z + v.w;
        sumsq += v.x*v.x + v.y*v.y + v.z*v.z + v.w*v.w;
    }
    for (int idx = tid; idx < BB*(OPOS/4); idx += 256) {
        const int b = idx / (OPOS/4), pos = idx % (OPOS/4);
        const float4 xv = *reinterpret_cast<const float4*>(
            &xin[((size_t)b*CC + c) * XROW + DPOS + pos*4]);
        const float4 ov = *reinterpret_cast<const float4*>(
            &obsout[((size_t)b*CC + c) * OPOS + pos*4]);
        const float4 v = make_float4(xv.x + fmaxf(ov.x, 0.f), xv.y + fmaxf(ov.y, 0.f),
                                     xv.z + fmaxf(ov.z, 0.f), xv.w + fmaxf(ov.w, 0.f));
        sum   += v.x + v.y + v.z + v.w;
        sumsq += v.x*v.x + v.y*v.y + v.z*v.z + v.w*v.w;
    }
    #pragma unroll
    for (int off = 32; off > 0; off >>= 1) {
        sum   += __shfl_xor(sum, off);
        sumsq += __shfl_xor(sumsq, off);
    }
    __shared__ float ssum[4], ssq[4];
    __shared__ float s_mean, s_inv;
    const int lane = tid & 63, w = tid >> 6;
    if (lane == 0) { ssum[w] = sum; ssq[w] = sumsq; }
    __syncthreads();
    if (tid == 0) {
        float s  = ssum[0] + ssum[1] + ssum[2] + ssum[3];
        float sq = ssq[0] + ssq[1] + ssq[2] + ssq[3];
        const float mean = s / 12544.f;
        const float var  = sq / 12544.f - mean * mean;
        s_mean = mean;
        s_inv  = rsqrtf(var + 1e-5f);
    }
    __syncthreads();
    const float mean = s_mean;
    const float gi = gamma[c] * s_inv;
    const float bt = beta[c];
    for (int idx = tid; idx < BB*(DPOS/4); idx += 256) {
        const int b = idx / (DPOS/4), pos = idx % (DPOS/4);
        const size_t o = ((size_t)b*CC + c) * XROW + pos*4;
        const float4 v = *reinterpret_cast<const float4*>(&xin[o]);
        const float4 r = make_float4((v.x-mean)*gi+bt, (v.y-mean)*gi+bt,
                                     (v.z-mean)*gi+bt, (v.w-mean)*gi+bt);
        *reinterpret_cast<float4*>(&xout[o]) = r;
    }
    for (int idx = tid; idx < BB*(OPOS/4); idx += 256) {
        const int b = idx / (OPOS/4), pos = idx % (OPOS/4);
        const float4 xv = *reinterpret_cast<const float4*>(
            &xin[((size_t)b*CC + c) * XROW + DPOS + pos*4]);
        const float4 ov = *reinterpret_cast<const float4*>(
            &obsout[((size_t)b*CC + c) * OPOS + pos*4]);
        const float4 v = make_float4(xv.x + fmaxf(ov.x, 0.f), xv.y + fmaxf(ov.y, 0.f),
                                     xv.z + fmaxf(ov.z, 0.f), xv.w + fmaxf(ov.w, 0.f));
        const float4 r = make_float4((v.x-mean)*gi+bt, (v.y-mean)*gi+bt,
                                     (v.z-mean)*gi+bt, (v.w-mean)*gi+bt);
        *reinterpret_cast<float4*>(&xout[((size_t)b*CC + c) * XROW + DPOS + pos*4]) = r;
    }
}

// ---------------------------------------------------------------------------
extern "C" void kernel_launch(void* const* d_in, const int* in_sizes, int n_in,
                              void* d_out, int out_size, void* d_ws, size_t ws_size,
                              hipStream_t stream)
{
    const float* x   = (const float*)d_in[0];
    const float* dqw = (const float*)d_in[1];
    const float* dkw = (const float*)d_in[2];
    const float* dvw = (const float*)d_in[3];
    const float* oqw = (const float*)d_in[4];
    const float* okw = (const float*)d_in[5];
    const float* ovw = (const float*)d_in[6];
    const float* oow = (const float*)d_in[7];
    const float* gam = (const float*)d_in[8];
    const float* bet = (const float*)d_in[9];

    const size_t XN = (size_t)BB * CC * TT * HW;   // 3,211,264
    const size_t DN = (size_t)BB * CC * DPOS;      //   802,816
    const size_t ON = (size_t)BB * CC * OPOS;      // 2,408,448
    const size_t WN = (size_t)3 * CC * CC;         //   196,608

    float*  xb0     = (float*)d_ws;
    float*  xb1     = xb0 + XN;
    float*  obsout  = xb1 + XN;
    ushort* XP      = (ushort*)(obsout + ON);     // [b][8][3136][32]
    ushort* QdP     = XP + XN;
    ushort* KdP     = QdP + DN;
    ushort* VdemoP  = KdP + DN;
    ushort* dvattP  = VdemoP + DN;
    ushort* QP      = dvattP + DN;
    ushort* KoP     = QP + ON;
    ushort* VoP     = KoP + ON;
    ushort* mergedP = VoP + ON;
    ushort* wpk     = mergedP + ON;
    ushort* dqwb = wpk;          ushort* dkwb = wpk + WN;   ushort* dvwb = wpk + 2*WN;
    ushort* oqwb = wpk + 3*WN;   ushort* okwb = wpk + 4*WN; ushort* ovwb = wpk + 5*WN;
    ushort* oowb = wpk + 6*WN;

    const dim3 blk(256);
    const dim3 blk2(512);
    const float QS = 0.0625f * 1.44269504f;   // (1/sqrt(C)) * log2(e) -> raw exp2 in attn

    // all 7 weight packs in one launch
    pack_w7<<<dim3(192, 7), blk, 0, stream>>>(
        dqw, dkw, dvw, oqw, okw, ovw, oow,
        dqwb, dkwb, dvwb, oqwb, okwb, ovwb, oowb, (int)(WN/4));

    for (int i = 0; i < 3; i++) {
        const float* xin  = (i == 0) ? x : (i == 1 ? xb0 : xb1);
        float*       xout = (i == 2) ? (float*)d_out : (i == 0 ? xb0 : xb1);
        const size_t wB = (size_t)i * CC * CC;

        // 1: pack x -> XP
        pack_T<<<dim3(49, 8, BB), blk, 0, stream>>>(xin, XP, XROW);

        // 2: demo projections (Q scaled by log2(e)/16 at pack)
        proj_mfma<<<dim3(BB*13, 4, 3), blk, 0, stream>>>(
            XP, XROW, 0, DPOS, DPOS,
            dqwb + wB, dkwb + wB, dvwb + wB,
            QdP, KdP, VdemoP, 0, 0, 1, QS, 1.f, 1.f);

        // 3: demo attention
        demo_attn_mfma<<<dim3(13, NHEADS, BB), blk2, 0, stream>>>(
            QdP, KdP, VdemoP, dvattP);

        // 4: obs projections (Q scaled by log2(e)/16 at pack)
        proj_mfma<<<dim3(BB*37, 4, 3), blk, 0, stream>>>(
            XP, XROW, DPOS, OPOS, OPOS,
            oqwb + wB, okwb + wB, ovwb + wB,
            QP, KoP, VoP, 0, 0, 1, QS, 1.f, 1.f);

        // 5: obs attention -> mergedP
        obs_attn_mfma<<<dim3(OBS_T, NHEADS, BB), blk2, 0, stream>>>(
            KdP, KoP, QP, dvattP, VoP, mergedP);

        // 6: output projection (fp32 out)
        proj_mfma<<<dim3(BB*37, 4, 1), blk, 0, stream>>>(
            mergedP, OPOS, 0, OPOS, OPOS,
            oowb + wB, oowb + wB, oowb + wB,
            obsout, obsout, obsout, 2, 2, 2, 1.f, 1.f, 1.f);

        // 7: residual + BN
        bn_fuse<<<dim3(CC), blk, 0, stream>>>(xin, obsout, gam + i*CC, bet + i*CC, xout);
    }
}

// Round 15
// 388.179 us; speedup vs baseline: 2.2993x; 1.0074x over previous
//
#include <hip/hip_runtime.h>
#include <hip/hip_bf16.h>

// Problem constants
#define BB 4
#define CC 256
#define TT 16
#define HW 196
#define DEMO_T 4
#define OBS_T 12
#define DPOS 784      // DEMO_T*HW
#define OPOS 2352     // OBS_T*HW
#define XROW 3136     // TT*HW
#define NHEADS 8
#define CH 32
#define NPOS 980      // DPOS + HW (cat keys per (b,t,n))

typedef float  f32x4 __attribute__((ext_vector_type(4)));
typedef short  s8v   __attribute__((ext_vector_type(8)));
typedef short  s4v   __attribute__((ext_vector_type(4)));

static __device__ __forceinline__ ushort f2bf(float f) {
    union { __hip_bfloat16 h; ushort u; } cv;
    cv.h = __float2bfloat16(f);
    return cv.u;
}
static __device__ __forceinline__ short bfr(float f) { return (short)f2bf(f); }

static __device__ __forceinline__ float fast_rcp(float x) {
#if __has_builtin(__builtin_amdgcn_rcpf)
    return __builtin_amdgcn_rcpf(x);
#else
    return 1.f / x;
#endif
}

static __device__ __forceinline__ float fexp2(float x) {
#if __has_builtin(__builtin_amdgcn_exp2f)
    return __builtin_amdgcn_exp2f(x);
#else
    return exp2f(x);
#endif
}

// DPP row-rotate add: allreduce-sum across an aligned 16-lane row.
template<int CTRL>
static __device__ __forceinline__ float dpp_add(float x) {
    union { float f; int i; } a, o;
    a.f = x;
    o.i = __builtin_amdgcn_update_dpp(0, a.i, CTRL, 0xF, 0xF, true);
    return x + o.f;
}
static __device__ __forceinline__ float row16_sum(float x) {
    x = dpp_add<0x128>(x);   // ror 8
    x = dpp_add<0x124>(x);   // ror 4
    x = dpp_add<0x122>(x);   // ror 2
    x = dpp_add<0x121>(x);   // ror 1
    return x;
}

static __device__ __forceinline__ f32x4 mfma_pv(s4v a, s4v b, f32x4 c) {
#if __has_builtin(__builtin_amdgcn_mfma_f32_16x16x16bf16_1k)
    return __builtin_amdgcn_mfma_f32_16x16x16bf16_1k(a, b, c, 0, 0, 0);
#else
    s8v a8 = {a[0], a[1], a[2], a[3], 0, 0, 0, 0};
    s8v b8 = {b[0], b[1], b[2], b[3], 0, 0, 0, 0};
    return __builtin_amdgcn_mfma_f32_16x16x32_bf16(a8, b8, c, 0, 0, 0);
#endif
}

// ---------------------------------------------------------------------------
// pack_T: fp32 [b][256][P] -> bf16 [b][8][P][32]  (layer-0 input pack only)
// ---------------------------------------------------------------------------
__global__ __launch_bounds__(256) void pack_T(
    const float* __restrict__ src, ushort* __restrict__ dst, int P)
{
    const int hn = blockIdx.y, bb = blockIdx.z;
    const int p0 = blockIdx.x * 64;
    __shared__ float L[32][73];
    const int tid = threadIdx.x;
    {
        const int c = tid >> 3, sg = tid & 7;
        const int p = p0 + sg*8;
        const float* s = src + ((size_t)bb*CC + hn*CH + c) * P + p;
        float4 a = {0,0,0,0}, b2 = {0,0,0,0};
        if (p < P) { a = *reinterpret_cast<const float4*>(s);
                     b2 = *reinterpret_cast<const float4*>(s + 4); }
        L[c][sg*8+0]=a.x;  L[c][sg*8+1]=a.y;  L[c][sg*8+2]=a.z;  L[c][sg*8+3]=a.w;
        L[c][sg*8+4]=b2.x; L[c][sg*8+5]=b2.y; L[c][sg*8+6]=b2.z; L[c][sg*8+7]=b2.w;
    }
    __syncthreads();
    {
        const int pl = tid >> 2, cs = (tid & 3) * 8;
        if (p0 + pl < P) {
            ushort o[8];
            #pragma unroll
            for (int j = 0; j < 8; j++) o[j] = f2bf(L[cs+j][pl]);
            uint4 v;
            v.x = o[0] | ((uint)o[1]<<16); v.y = o[2] | ((uint)o[3]<<16);
            v.z = o[4] | ((uint)o[5]<<16); v.w = o[6] | ((uint)o[7]<<16);
            *reinterpret_cast<uint4*>(dst + (((size_t)bb*NHEADS + hn)*P + p0 + pl)*32 + cs) = v;
        }
    }
}

// ---------------------------------------------------------------------------
// pack_w7: all 7 weight tensors fp32 -> bf16 in ONE launch (y selects pair)
// ---------------------------------------------------------------------------
__global__ __launch_bounds__(256) void pack_w7(
    const float* __restrict__ s0, const float* __restrict__ s1,
    const float* __restrict__ s2, const float* __restrict__ s3,
    const float* __restrict__ s4, const float* __restrict__ s5,
    const float* __restrict__ s6,
    ushort* __restrict__ d0, ushort* __restrict__ d1, ushort* __restrict__ d2,
    ushort* __restrict__ d3, ushort* __restrict__ d4, ushort* __restrict__ d5,
    ushort* __restrict__ d6, int n4)
{
    const float* src; ushort* dst;
    switch (blockIdx.y) {
        case 0: src = s0; dst = d0; break;
        case 1: src = s1; dst = d1; break;
        case 2: src = s2; dst = d2; break;
        case 3: src = s3; dst = d3; break;
        case 4: src = s4; dst = d4; break;
        case 5: src = s5; dst = d5; break;
        default: src = s6; dst = d6; break;
    }
    for (size_t i = (size_t)blockIdx.x * 256 + threadIdx.x; i < (size_t)n4;
         i += (size_t)gridDim.x * 256) {
        const float4 v = *reinterpret_cast<const float4*>(src + i*4);
        uint2 o;
        o.x = f2bf(v.x) | ((uint)f2bf(v.y) << 16);
        o.y = f2bf(v.z) | ((uint)f2bf(v.w) << 16);
        *reinterpret_cast<uint2*>(dst + i*4) = o;
    }
}

// ---------------------------------------------------------------------------
// bf16 MFMA projection GEMM with fused pack epilogues (+ per-z output scale).
//   variant 0 = packed-T bf16 [b][8][OP][32]; 1 = natural bf16 [b][256][OP];
//   2 = natural fp32 [b][256][OP];
//   3 = fp32 v = resid_obs + relu(acc)  (fused residual-ReLU out-projection)
// ---------------------------------------------------------------------------
__global__ __launch_bounds__(256) void proj_mfma(
    const ushort* __restrict__ XPK, int P, int pOff, int ncols, int OP,
    const ushort* __restrict__ W0, const ushort* __restrict__ W1, const ushort* __restrict__ W2,
    void* __restrict__ O0, void* __restrict__ O1, void* __restrict__ O2,
    int v0, int v1, int v2, float sc0, float sc1, float sc2,
    const float* __restrict__ resid)
{
    const int ptiles = (ncols + 63) >> 6;
    const int b  = blockIdx.x / ptiles;
    const int pt = blockIdx.x % ptiles;
    const int fbase = blockIdx.y * 64;
    const int z = blockIdx.z;
    const ushort* W = (z == 0) ? W0 : (z == 1) ? W1 : W2;
    void*        O = (z == 0) ? O0 : (z == 1) ? O1 : O2;
    const int variant = (z == 0) ? v0 : (z == 1) ? v1 : v2;
    const float sc    = (z == 0) ? sc0 : (z == 1) ? sc1 : sc2;

    const int tid = threadIdx.x, lane = tid & 63, w = tid >> 6;
    const int l15 = lane & 15, grp = lane >> 4;

    __shared__ float Cf[64][68];

    f32x4 acc[4];
    #pragma unroll
    for (int nt = 0; nt < 4; ++nt) acc[nt] = (f32x4){0.f, 0.f, 0.f, 0.f};

    const ushort* Wrow = W + (size_t)(fbase + w*16 + l15) * CC;
    int prow[4];
    #pragma unroll
    for (int nt = 0; nt < 4; ++nt) {
        const int p = pt*64 + nt*16 + l15;
        prow[nt] = (p < ncols) ? p : (ncols - 1);   // clamp: dup rows discarded
    }
    const size_t xb = (size_t)b * 8;

    #pragma unroll
    for (int kc = 0; kc < 8; ++kc) {
        const s8v aW = *reinterpret_cast<const s8v*>(Wrow + kc*32 + grp*8);
        #pragma unroll
        for (int nt = 0; nt < 4; ++nt) {
            const s8v bX = *reinterpret_cast<const s8v*>(
                XPK + ((xb + kc)*P + pOff + prow[nt])*32 + grp*8);
            acc[nt] = __builtin_amdgcn_mfma_f32_16x16x32_bf16(aW, bX, acc[nt], 0, 0, 0);
        }
    }
    #pragma unroll
    for (int nt = 0; nt < 4; ++nt)
        #pragma unroll
        for (int r = 0; r < 4; ++r)
            Cf[w*16 + grp*4 + r][nt*16 + l15] = acc[nt][r] * sc;
    __syncthreads();

    if (variant == 0) {
        ushort* dst = (ushort*)O;
        const int p_l = tid >> 2, c8 = (tid & 3) * 8;
        const int opos = pt*64 + p_l;
        if (opos < ncols) {
            #pragma unroll
            for (int hq = 0; hq < 2; ++hq) {
                ushort e[8];
                #pragma unroll
                for (int j = 0; j < 8; ++j) e[j] = f2bf(Cf[hq*32 + c8 + j][p_l]);
                uint4 v;
                v.x = e[0] | ((uint)e[1]<<16); v.y = e[2] | ((uint)e[3]<<16);
                v.z = e[4] | ((uint)e[5]<<16); v.w = e[6] | ((uint)e[7]<<16);
                *reinterpret_cast<uint4*>(
                    dst + (((size_t)b*NHEADS + (fbase >> 5) + hq)*OP + opos)*32 + c8) = v;
            }
        }
    } else if (variant == 1) {
        ushort* dst = (ushort*)O;
        #pragma unroll
        for (int pass = 0; pass < 2; ++pass) {
            const int idx = pass*256 + tid;
            const int f_l = idx >> 3, u = idx & 7;
            const int p0 = pt*64 + u*8;
            if (p0 < ncols) {
                ushort e[8];
                #pragma unroll
                for (int j = 0; j < 8; ++j) e[j] = f2bf(Cf[f_l][u*8 + j]);
                uint4 v;
                v.x = e[0] | ((uint)e[1]<<16); v.y = e[2] | ((uint)e[3]<<16);
                v.z = e[4] | ((uint)e[5]<<16); v.w = e[6] | ((uint)e[7]<<16);
                *reinterpret_cast<uint4*>(
                    dst + ((size_t)b*CC + fbase + f_l)*OP + p0) = v;
            }
        }
    } else if (variant == 2) {
        float* dst = (float*)O;
        #pragma unroll
        for (int pass = 0; pass < 2; ++pass) {
            const int idx = pass*256 + tid;
            const int f_l = idx >> 3, u = idx & 7;
            const int p0 = pt*64 + u*8;
            if (p0 < ncols) {
                float* dp = dst + ((size_t)b*CC + fbase + f_l)*OP + p0;
                *reinterpret_cast<float4*>(dp)     = *reinterpret_cast<const float4*>(&Cf[f_l][u*8]);
                *reinterpret_cast<float4*>(dp + 4) = *reinterpret_cast<const float4*>(&Cf[f_l][u*8 + 4]);
            }
        }
    } else {
        // variant 3: v = resid_obs + relu(acc), fp32
        float* dst = (float*)O;
        #pragma unroll
        for (int pass = 0; pass < 2; ++pass) {
            const int idx = pass*256 + tid;
            const int f_l = idx >> 3, u = idx & 7;
            const int p0 = pt*64 + u*8;
            if (p0 < ncols) {
                const float* rp = resid + ((size_t)b*CC + fbase + f_l)*XROW + DPOS + p0;
                const float4 r0 = *reinterpret_cast<const float4*>(rp);
                const float4 r1 = *reinterpret_cast<const float4*>(rp + 4);
                float* dp = dst + ((size_t)b*CC + fbase + f_l)*OP + p0;
                const float4 o0 = make_float4(
                    r0.x + fmaxf(Cf[f_l][u*8+0], 0.f), r0.y + fmaxf(Cf[f_l][u*8+1], 0.f),
                    r0.z + fmaxf(Cf[f_l][u*8+2], 0.f), r0.w + fmaxf(Cf[f_l][u*8+3], 0.f));
                const float4 o1 = make_float4(
                    r1.x + fmaxf(Cf[f_l][u*8+4], 0.f), r1.y + fmaxf(Cf[f_l][u*8+5], 0.f),
                    r1.z + fmaxf(Cf[f_l][u*8+6], 0.f), r1.w + fmaxf(Cf[f_l][u*8+7], 0.f));
                *reinterpret_cast<float4*>(dp)     = o0;
                *reinterpret_cast<float4*>(dp + 4) = o1;
            }
        }
    }
}

// ---------------------------------------------------------------------------
// Demo attention — bf16 MFMA, 512 threads, NO-MAX softmax, barrier-free,
// flat (ch,jt) loop with REGISTER PREFETCH of next-iter Q/V fragments.
// Q pre-scaled log2(e)/16 -> raw exp2.
// ---------------------------------------------------------------------------
__global__ __launch_bounds__(512) void demo_attn_mfma(
    const ushort* __restrict__ QdP, const ushort* __restrict__ KdP,
    const ushort* __restrict__ VdP, ushort* __restrict__ dvattP)
{
    const int ib = blockIdx.x, hn = blockIdx.y, bb = blockIdx.z;
    const int tid = threadIdx.x;
    const int g   = tid >> 8;          // j-half
    const int gt  = tid & 255;
    const int lane = tid & 63;
    const int w    = (tid >> 6) & 3;   // i-quarter
    const int l15 = lane & 15, grp = lane >> 4;

    __shared__ float mrg[2304];                       // Lb[256] Ob[2048]
    __shared__ __align__(16) ushort OutS[32*72];

    const size_t hBase = ((size_t)bb*NHEADS + hn) * DPOS;
    const size_t vRow0 = ((size_t)bb*CC + hn*CH) * DPOS;

    const int i_glob = ib*64 + w*16 + l15;
    const s8v bK = *reinterpret_cast<const s8v*>(KdP + (hBase + i_glob)*32 + grp*8);

    f32x4 accO[2] = {{0.f,0.f,0.f,0.f}, {0.f,0.f,0.f,0.f}};
    float l_run = 0.f;

    const int chBase = g ? 7 : 0;
    const int iters  = g ? 21 : 28;    // (13th chunk has 1 jt)

    auto qAddr = [&](int it) -> const ushort* {
        const int ch = chBase + (it >> 2), jt = it & 3;
        return QdP + (hBase + ch*64 + jt*16 + l15)*32 + grp*8;
    };
    auto vAddr = [&](int it, int ct) -> const ushort* {
        const int ch = chBase + (it >> 2), jt = it & 3;
        return VdP + vRow0 + (size_t)(ct*16 + l15)*DPOS + ch*64 + jt*16 + grp*4;
    };

    s8v curQ  = *reinterpret_cast<const s8v*>(qAddr(0));
    s4v curV0 = *reinterpret_cast<const s4v*>(vAddr(0, 0));
    s4v curV1 = *reinterpret_cast<const s4v*>(vAddr(0, 1));

    for (int it = 0; it < iters; ++it) {
        s8v nQ; s4v nV0, nV1;
        if (it + 1 < iters) {
            nQ  = *reinterpret_cast<const s8v*>(qAddr(it + 1));
            nV0 = *reinterpret_cast<const s4v*>(vAddr(it + 1, 0));
            nV1 = *reinterpret_cast<const s4v*>(vAddr(it + 1, 1));
        }
        const f32x4 z = {0.f,0.f,0.f,0.f};
        const f32x4 st = __builtin_amdgcn_mfma_f32_16x16x32_bf16(curQ, bK, z, 0, 0, 0);
        const float e0 = fexp2(st[0]), e1 = fexp2(st[1]);
        const float e2 = fexp2(st[2]), e3 = fexp2(st[3]);
        l_run += (e0 + e1) + (e2 + e3);
        s4v pf4;
        pf4[0] = bfr(e0); pf4[1] = bfr(e1); pf4[2] = bfr(e2); pf4[3] = bfr(e3);
        accO[0] = mfma_pv(curV0, pf4, accO[0]);
        accO[1] = mfma_pv(curV1, pf4, accO[1]);
        curQ = nQ; curV0 = nV0; curV1 = nV1;
    }
    // cross-grp partial-l reduce
    l_run += __shfl_xor(l_run, 16);
    l_run += __shfl_xor(l_run, 32);

    // ---- merge: (l, O) add across groups, then normalize ----
    float* Lb = mrg;          // [256]
    float* Ob = mrg + 256;    // [256][8]
    if (g == 1) {
        Lb[w*64 + lane] = l_run;
        #pragma unroll
        for (int ct = 0; ct < 2; ++ct)
            #pragma unroll
            for (int r = 0; r < 4; ++r)
                Ob[(w*64 + lane)*8 + ct*4 + r] = accO[ct][r];
    }
    __syncthreads();
    if (g == 0) {
        const float linv = 1.f / (l_run + Lb[w*64 + lane]);
        #pragma unroll
        for (int ct = 0; ct < 2; ++ct)
            #pragma unroll
            for (int r = 0; r < 4; ++r) {
                const float o = (accO[ct][r] + Ob[(w*64 + lane)*8 + ct*4 + r]) * linv;
                OutS[(ct*16 + grp*4 + r)*72 + w*16 + l15] = f2bf(o);
            }
    }
    __syncthreads();
    if (g == 0) {
        const int c = gt >> 3, sg = gt & 7;
        const int col = ib*64 + sg*8;
        if (col < DPOS) {
            const uint4 v = *reinterpret_cast<const uint4*>(&OutS[c*72 + sg*8]);
            *reinterpret_cast<uint4*>(dvattP + vRow0 + (size_t)c*DPOS + col) = v;
        }
    }
}

// ---------------------------------------------------------------------------
// Obs attention per (b, t, n) — round-11 structure (proven 48 µs): 512 thr,
// barrier-free main loop + register prefetch, NO-MAX softmax, DPP reduce.
// ---------------------------------------------------------------------------
__global__ __launch_bounds__(512) void obs_attn_mfma(
    const ushort* __restrict__ KdP, const ushort* __restrict__ KoP,
    const ushort* __restrict__ QP,  const ushort* __restrict__ VdP,
    const ushort* __restrict__ VoP, ushort* __restrict__ mergedP)
{
    const int tt = blockIdx.x, hn = blockIdx.y, bb = blockIdx.z;
    __shared__ __align__(16) ushort smem_u[27136];   // QT[208][40] ∪ Ored[2][32][212]f32
    ushort* QT = smem_u;

    const int tid  = threadIdx.x;
    const int g    = tid >> 8;
    const int lane = tid & 63;
    const int w    = (tid >> 6) & 3;
    const int l15  = lane & 15, grp = lane >> 4;

    const size_t kdBase = ((size_t)bb*NHEADS + hn) * DPOS * 32;
    const size_t koBase = ((size_t)bb*NHEADS + hn) * OPOS * 32 + (size_t)tt*HW*32;
    const size_t vdRow0 = ((size_t)bb*CC + hn*CH) * DPOS;
    const size_t voRow0 = ((size_t)bb*CC + hn*CH) * OPOS + (size_t)tt*HW;

    auto loadK = [&](int p0) -> s8v {
        const int pk = p0 + l15;
        s8v v = {0,0,0,0,0,0,0,0};
        if (pk < NPOS) {
            const ushort* kp = (pk < DPOS)
                ? KdP + kdBase + (size_t)pk*32
                : KoP + koBase + (size_t)(pk - DPOS)*32;
            v = *reinterpret_cast<const s8v*>(kp + grp*8);
        }
        return v;
    };
    auto loadV = [&](int ct, int p0) -> s4v {
        const int c  = ct*16 + l15;
        const int pv = p0 + grp*4;
        s4v v = {0,0,0,0};
        if (pv < NPOS) {
            const ushort* vp = (pv < DPOS)
                ? VdP + vdRow0 + (size_t)c*DPOS + pv
                : VoP + voRow0 + (size_t)c*OPOS + (pv - DPOS);
            v = *reinterpret_cast<const s4v*>(vp);
        }
        return v;
    };

    // stage Q once (rows >= 196 zero)
    for (int idx = tid; idx < 832; idx += 512) {
        const int r = idx >> 2, sg = idx & 3;
        uint4 v = {0,0,0,0};
        if (r < HW) v = *reinterpret_cast<const uint4*>(QP + koBase + (size_t)r*32 + sg*8);
        *reinterpret_cast<uint4*>(&QT[r*40 + sg*8]) = v;
    }

    f32x4 accO[2][13];
    #pragma unroll
    for (int ct = 0; ct < 2; ++ct)
        #pragma unroll
        for (int qt = 0; qt < 13; ++qt)
            accO[ct][qt] = (f32x4){0.f, 0.f, 0.f, 0.f};

    const int pw = (g*4 + w) * 128;
    s8v curK  = loadK(pw);
    s4v curV0 = loadV(0, pw);
    s4v curV1 = loadV(1, pw);
    __syncthreads();

    for (int s = 0; s < 8; ++s) {
        s8v nK = {0,0,0,0,0,0,0,0};
        s4v nV0 = {0,0,0,0}, nV1 = {0,0,0,0};
        if (s < 7) {
            const int np = pw + (s+1)*16;
            nK  = loadK(np);
            nV0 = loadV(0, np);
            nV1 = loadV(1, np);
        }
        f32x4 ss[13];
        #pragma unroll
        for (int qt = 0; qt < 13; ++qt) {
            const s8v bQ = *reinterpret_cast<const s8v*>(&QT[(qt*16 + l15)*40 + grp*8]);
            const f32x4 z = {0.f, 0.f, 0.f, 0.f};
            ss[qt] = __builtin_amdgcn_mfma_f32_16x16x32_bf16(curK, bQ, z, 0, 0, 0);
        }
        #pragma unroll
        for (int r = 0; r < 4; ++r) {
            #pragma unroll
            for (int qt = 0; qt < 13; ++qt) ss[qt][r] = fexp2(ss[qt][r]);
            if (l15 >= 4) ss[12][r] = 0.f;   // q >= 196 pad
            float sum = ((((ss[0][r]+ss[1][r]) + (ss[2][r]+ss[3][r]))
                        + ((ss[4][r]+ss[5][r]) + (ss[6][r]+ss[7][r])))
                        + (((ss[8][r]+ss[9][r]) + (ss[10][r]+ss[11][r])) + ss[12][r]));
            sum = row16_sum(sum);
            const float is = fast_rcp(sum);
            #pragma unroll
            for (int qt = 0; qt < 13; ++qt) ss[qt][r] *= is;
        }
        s4v pf[13];
        #pragma unroll
        for (int qt = 0; qt < 13; ++qt) {
            s4v p4;
            #pragma unroll
            for (int r = 0; r < 4; ++r) p4[r] = bfr(ss[qt][r]);
            pf[qt] = p4;
        }
        #pragma unroll
        for (int qt = 0; qt < 13; ++qt)
            accO[0][qt] = mfma_pv(curV0, pf[qt], accO[0][qt]);
        #pragma unroll
        for (int qt = 0; qt < 13; ++qt)
            accO[1][qt] = mfma_pv(curV1, pf[qt], accO[1][qt]);

        curK = nK; curV0 = nV0; curV1 = nV1;
    }
    __syncthreads();

    // ---- per-group 4-wave reduction into Ored[g] ----
    float* OredF = reinterpret_cast<float*>(smem_u);   // [2][32][212]
    float* Og = OredF + g * 6784;
    for (int wv = 0; wv < 4; ++wv) {
        if (w == wv) {
            #pragma unroll
            for (int ct = 0; ct < 2; ++ct)
                #pragma unroll
                for (int qt = 0; qt < 13; ++qt)
                    #pragma unroll
                    for (int r = 0; r < 4; ++r) {
                        const int c = ct*16 + grp*4 + r;
                        const int q = qt*16 + l15;
                        if (wv == 0) Og[c*212 + q]  = accO[ct][qt][r];
                        else         Og[c*212 + q] += accO[ct][qt][r];
                    }
        }
        __syncthreads();
    }
    for (int idx = tid; idx < HW*4; idx += 512) {
        const int q = idx >> 2, c8 = (idx & 3) * 8;
        ushort e[8];
        #pragma unroll
        for (int j = 0; j < 8; ++j) {
            const int c = c8 + j;
            e[j] = f2bf(OredF[c*212 + q] + OredF[6784 + c*212 + q]);
        }
        uint4 v;
        v.x = e[0] | ((uint)e[1]<<16); v.y = e[2] | ((uint)e[3]<<16);
        v.z = e[4] | ((uint)e[5]<<16); v.w = e[6] | ((uint)e[7]<<16);
        *reinterpret_cast<uint4*>(
            mergedP + (((size_t)bb*NHEADS + hn)*OPOS + (size_t)tt*HW + q)*32 + c8) = v;
    }
}

// ---------------------------------------------------------------------------
// bn_stats: per-channel mean/rstd over cat(xin_demo, v). One block/channel.
// v = obs_new (residual+ReLU already fused into the out-projection).
// ---------------------------------------------------------------------------
__global__ __launch_bounds__(256) void bn_stats(
    const float* __restrict__ xin, const float* __restrict__ v,
    float2* __restrict__ stats)
{
    const int c = blockIdx.x;
    const int tid = threadIdx.x;
    float sum = 0.f, sumsq = 0.f;
    for (int idx = tid; idx < BB*(DPOS/4); idx += 256) {
        const int b = idx / (DPOS/4), pos = idx % (DPOS/4);
        const float4 x4 = *reinterpret_cast<const float4*>(
            &xin[((size_t)b*CC + c) * XROW + pos*4]);
        sum   += x4.x + x4.y + x4.z + x4.w;
        sumsq += x4.x*x4.x + x4.y*x4.y + x4.z*x4.z + x4.w*x4.w;
    }
    for (int idx = tid; idx < BB*(OPOS/4); idx += 256) {
        const int b = idx / (OPOS/4), pos = idx % (OPOS/4);
        const float4 v4 = *reinterpret_cast<const float4*>(
            &v[((size_t)b*CC + c) * OPOS + pos*4]);
        sum   += v4.x + v4.y + v4.z + v4.w;
        sumsq += v4.x*v4.x + v4.y*v4.y + v4.z*v4.z + v4.w*v4.w;
    }
    #pragma unroll
    for (int off = 32; off > 0; off >>= 1) {
        sum   += __shfl_xor(sum, off);
        sumsq += __shfl_xor(sumsq, off);
    }
    __shared__ float ssum[4], ssq[4];
    const int lane = tid & 63, w = tid >> 6;
    if (lane == 0) { ssum[w] = sum; ssq[w] = sumsq; }
    __syncthreads();
    if (tid == 0) {
        const float s  = ssum[0] + ssum[1] + ssum[2] + ssum[3];
        const float sq = ssq[0] + ssq[1] + ssq[2] + ssq[3];
        const float mean = s / 12544.f;
        const float var  = sq / 12544.f - mean * mean;
        stats[c] = make_float2(mean, rsqrtf(var + 1e-5f));
    }
}

// ---------------------------------------------------------------------------
// bn_apply: normalize cat(xin_demo, v) -> xout fp32, and (optionally) emit
// next layer's packed-T bf16 XP via LDS transpose (fuses pack_T).
// Grid (49 p-tiles, 8 c-chunks, B), 256 thr.
// ---------------------------------------------------------------------------
__global__ __launch_bounds__(256) void bn_apply(
    const float* __restrict__ xin, const float* __restrict__ v,
    const float2* __restrict__ stats,
    const float* __restrict__ gamma, const float* __restrict__ beta,
    float* __restrict__ xout, ushort* __restrict__ XPdst)
{
    const int hn = blockIdx.y, bb = blockIdx.z;
    const int p0 = blockIdx.x * 64;
    __shared__ float L[32][73];
    const int tid = threadIdx.x;
    const int c  = tid >> 3, sg = tid & 7;
    const int cg = hn*CH + c;
    const float2 st = stats[cg];
    const float gi  = gamma[cg] * st.y;
    const float bt  = beta[cg];
    const int p = p0 + sg*8;

    float vals[8];
    if (p + 7 < DPOS) {
        const float* s = xin + ((size_t)bb*CC + cg) * XROW + p;
        const float4 a = *reinterpret_cast<const float4*>(s);
        const float4 b2 = *reinterpret_cast<const float4*>(s + 4);
        vals[0]=a.x; vals[1]=a.y; vals[2]=a.z; vals[3]=a.w;
        vals[4]=b2.x; vals[5]=b2.y; vals[6]=b2.z; vals[7]=b2.w;
    } else if (p >= DPOS) {
        const float* s = v + ((size_t)bb*CC + cg) * OPOS + (p - DPOS);
        const float4 a = *reinterpret_cast<const float4*>(s);
        const float4 b2 = *reinterpret_cast<const float4*>(s + 4);
        vals[0]=a.x; vals[1]=a.y; vals[2]=a.z; vals[3]=a.w;
        vals[4]=b2.x; vals[5]=b2.y; vals[6]=b2.z; vals[7]=b2.w;
    } else {
        #pragma unroll
        for (int j = 0; j < 8; ++j) {
            const int pp = p + j;
            vals[j] = (pp < DPOS)
                ? xin[((size_t)bb*CC + cg) * XROW + pp]
                : v[((size_t)bb*CC + cg) * OPOS + (pp - DPOS)];
        }
    }
    float4 o0, o1;
    o0.x = (vals[0]-st.x)*gi + bt; o0.y = (vals[1]-st.x)*gi + bt;
    o0.z = (vals[2]-st.x)*gi + bt; o0.w = (vals[3]-st.x)*gi + bt;
    o1.x = (vals[4]-st.x)*gi + bt; o1.y = (vals[5]-st.x)*gi + bt;
    o1.z = (vals[6]-st.x)*gi + bt; o1.w = (vals[7]-st.x)*gi + bt;
    {
        float* dp = xout + ((size_t)bb*CC + cg) * XROW + p;
        *reinterpret_cast<float4*>(dp)     = o0;
        *reinterpret_cast<float4*>(dp + 4) = o1;
    }
    if (XPdst) {
        L[c][sg*8+0]=o0.x; L[c][sg*8+1]=o0.y; L[c][sg*8+2]=o0.z; L[c][sg*8+3]=o0.w;
        L[c][sg*8+4]=o1.x; L[c][sg*8+5]=o1.y; L[c][sg*8+6]=o1.z; L[c][sg*8+7]=o1.w;
        __syncthreads();
        const int pl = tid >> 2, cs = (tid & 3) * 8;
        ushort e[8];
        #pragma unroll
        for (int j = 0; j < 8; j++) e[j] = f2bf(L[cs+j][pl]);
        uint4 vv;
        vv.x = e[0] | ((uint)e[1]<<16); vv.y = e[2] | ((uint)e[3]<<16);
        vv.z = e[4] | ((uint)e[5]<<16); vv.w = e[6] | ((uint)e[7]<<16);
        *reinterpret_cast<uint4*>(
            XPdst + (((size_t)bb*NHEADS + hn)*XROW + p0 + pl)*32 + cs) = vv;
    }
}

// ---------------------------------------------------------------------------
extern "C" void kernel_launch(void* const* d_in, const int* in_sizes, int n_in,
                              void* d_out, int out_size, void* d_ws, size_t ws_size,
                              hipStream_t stream)
{
    const float* x   = (const float*)d_in[0];
    const float* dqw = (const float*)d_in[1];
    const float* dkw = (const float*)d_in[2];
    const float* dvw = (const float*)d_in[3];
    const float* oqw = (const float*)d_in[4];
    const float* okw = (const float*)d_in[5];
    const float* ovw = (const float*)d_in[6];
    const float* oow = (const float*)d_in[7];
    const float* gam = (const float*)d_in[8];
    const float* bet = (const float*)d_in[9];

    const size_t XN = (size_t)BB * CC * TT * HW;   // 3,211,264
    const size_t DN = (size_t)BB * CC * DPOS;      //   802,816
    const size_t ON = (size_t)BB * CC * OPOS;      // 2,408,448
    const size_t WN = (size_t)3 * CC * CC;         //   196,608

    float*  xb0     = (float*)d_ws;
    float*  xb1     = xb0 + XN;
    float*  obsout  = xb1 + XN;                   // holds v = obs_new
    ushort* XP      = (ushort*)(obsout + ON);     // [b][8][3136][32]
    ushort* QdP     = XP + XN;
    ushort* KdP     = QdP + DN;
    ushort* VdemoP  = KdP + DN;
    ushort* dvattP  = VdemoP + DN;
    ushort* QP      = dvattP + DN;
    ushort* KoP     = QP + ON;
    ushort* VoP     = KoP + ON;
    ushort* mergedP = VoP + ON;
    ushort* wpk     = mergedP + ON;
    ushort* dqwb = wpk;          ushort* dkwb = wpk + WN;   ushort* dvwb = wpk + 2*WN;
    ushort* oqwb = wpk + 3*WN;   ushort* okwb = wpk + 4*WN; ushort* ovwb = wpk + 5*WN;
    ushort* oowb = wpk + 6*WN;
    float2* statsB = (float2*)(wpk + 7*WN);       // 256 float2

    const dim3 blk(256);
    const dim3 blk2(512);
    const float QS = 0.0625f * 1.44269504f;   // (1/sqrt(C)) * log2(e) -> raw exp2 in attn

    pack_w7<<<dim3(192, 7), blk, 0, stream>>>(
        dqw, dkw, dvw, oqw, okw, ovw, oow,
        dqwb, dkwb, dvwb, oqwb, okwb, ovwb, oowb, (int)(WN/4));

    // initial input pack (layers 1-2 get XP from bn_apply)
    pack_T<<<dim3(49, 8, BB), blk, 0, stream>>>(x, XP, XROW);

    for (int i = 0; i < 3; i++) {
        const float* xin  = (i == 0) ? x : (i == 1 ? xb0 : xb1);
        float*       xout = (i == 2) ? (float*)d_out : (i == 0 ? xb0 : xb1);
        const size_t wB = (size_t)i * CC * CC;

        // 1: demo projections (Q scaled by log2(e)/16 at pack)
        proj_mfma<<<dim3(BB*13, 4, 3), blk, 0, stream>>>(
            XP, XROW, 0, DPOS, DPOS,
            dqwb + wB, dkwb + wB, dvwb + wB,
            QdP, KdP, VdemoP, 0, 0, 1, QS, 1.f, 1.f, nullptr);

        // 2: demo attention
        demo_attn_mfma<<<dim3(13, NHEADS, BB), blk2, 0, stream>>>(
            QdP, KdP, VdemoP, dvattP);

        // 3: obs projections (Q scaled by log2(e)/16 at pack)
        proj_mfma<<<dim3(BB*37, 4, 3), blk, 0, stream>>>(
            XP, XROW, DPOS, OPOS, OPOS,
            oqwb + wB, okwb + wB, ovwb + wB,
            QP, KoP, VoP, 0, 0, 1, QS, 1.f, 1.f, nullptr);

        // 4: obs attention -> mergedP
        obs_attn_mfma<<<dim3(OBS_T, NHEADS, BB), blk2, 0, stream>>>(
            KdP, KoP, QP, dvattP, VoP, mergedP);

        // 5: output projection, fused residual+ReLU -> v (fp32)
        proj_mfma<<<dim3(BB*37, 4, 1), blk, 0, stream>>>(
            mergedP, OPOS, 0, OPOS, OPOS,
            oowb + wB, oowb + wB, oowb + wB,
            obsout, obsout, obsout, 3, 3, 3, 1.f, 1.f, 1.f, xin);

        // 6: BN stats
        bn_stats<<<dim3(CC), blk, 0, stream>>>(xin, obsout, statsB);

        // 7: BN apply (+ pack next layer's XP; final layer skips XP)
        bn_apply<<<dim3(49, 8, BB), blk, 0, stream>>>(
            xin, obsout, statsB, gam + i*CC, bet + i*CC, xout,
            (i < 2) ? XP : nullptr);
    }
}

// Round 16
// 382.443 us; speedup vs baseline: 2.3338x; 1.0150x over previous
//
#include <hip/hip_runtime.h>
#include <hip/hip_bf16.h>

// Problem constants
#define BB 4
#define CC 256
#define TT 16
#define HW 196
#define DEMO_T 4
#define OBS_T 12
#define DPOS 784      // DEMO_T*HW
#define OPOS 2352     // OBS_T*HW
#define XROW 3136     // TT*HW
#define NHEADS 8
#define CH 32
#define NPOS 980      // DPOS + HW (cat keys per (b,t,n))

typedef float  f32x4 __attribute__((ext_vector_type(4)));
typedef short  s8v   __attribute__((ext_vector_type(8)));
typedef short  s4v   __attribute__((ext_vector_type(4)));

static __device__ __forceinline__ ushort f2bf(float f) {
    union { __hip_bfloat16 h; ushort u; } cv;
    cv.h = __float2bfloat16(f);
    return cv.u;
}
static __device__ __forceinline__ short bfr(float f) { return (short)f2bf(f); }
static __device__ __forceinline__ float bf2f(short u) {
    union { uint u; float f; } cv;
    cv.u = ((uint)(ushort)u) << 16;
    return cv.f;
}

static __device__ __forceinline__ float fast_rcp(float x) {
#if __has_builtin(__builtin_amdgcn_rcpf)
    return __builtin_amdgcn_rcpf(x);
#else
    return 1.f / x;
#endif
}

static __device__ __forceinline__ float fexp2(float x) {
#if __has_builtin(__builtin_amdgcn_exp2f)
    return __builtin_amdgcn_exp2f(x);
#else
    return exp2f(x);
#endif
}

// DPP row-rotate add: allreduce-sum across an aligned 16-lane row.
template<int CTRL>
static __device__ __forceinline__ float dpp_add(float x) {
    union { float f; int i; } a, o;
    a.f = x;
    o.i = __builtin_amdgcn_update_dpp(0, a.i, CTRL, 0xF, 0xF, true);
    return x + o.f;
}
static __device__ __forceinline__ float row16_sum(float x) {
    x = dpp_add<0x128>(x);   // ror 8
    x = dpp_add<0x124>(x);   // ror 4
    x = dpp_add<0x122>(x);   // ror 2
    x = dpp_add<0x121>(x);   // ror 1
    return x;
}

static __device__ __forceinline__ f32x4 mfma_pv(s4v a, s4v b, f32x4 c) {
#if __has_builtin(__builtin_amdgcn_mfma_f32_16x16x16bf16_1k)
    return __builtin_amdgcn_mfma_f32_16x16x16bf16_1k(a, b, c, 0, 0, 0);
#else
    s8v a8 = {a[0], a[1], a[2], a[3], 0, 0, 0, 0};
    s8v b8 = {b[0], b[1], b[2], b[3], 0, 0, 0, 0};
    return __builtin_amdgcn_mfma_f32_16x16x32_bf16(a8, b8, c, 0, 0, 0);
#endif
}

// ---------------------------------------------------------------------------
// pack_T: fp32 [b][256][P] -> bf16 [b][8][P][32]  (layer-0 input pack only)
// ---------------------------------------------------------------------------
__global__ __launch_bounds__(256) void pack_T(
    const float* __restrict__ src, ushort* __restrict__ dst, int P)
{
    const int hn = blockIdx.y, bb = blockIdx.z;
    const int p0 = blockIdx.x * 64;
    __shared__ float L[32][73];
    const int tid = threadIdx.x;
    {
        const int c = tid >> 3, sg = tid & 7;
        const int p = p0 + sg*8;
        const float* s = src + ((size_t)bb*CC + hn*CH + c) * P + p;
        float4 a = {0,0,0,0}, b2 = {0,0,0,0};
        if (p < P) { a = *reinterpret_cast<const float4*>(s);
                     b2 = *reinterpret_cast<const float4*>(s + 4); }
        L[c][sg*8+0]=a.x;  L[c][sg*8+1]=a.y;  L[c][sg*8+2]=a.z;  L[c][sg*8+3]=a.w;
        L[c][sg*8+4]=b2.x; L[c][sg*8+5]=b2.y; L[c][sg*8+6]=b2.z; L[c][sg*8+7]=b2.w;
    }
    __syncthreads();
    {
        const int pl = tid >> 2, cs = (tid & 3) * 8;
        if (p0 + pl < P) {
            ushort o[8];
            #pragma unroll
            for (int j = 0; j < 8; j++) o[j] = f2bf(L[cs+j][pl]);
            uint4 v;
            v.x = o[0] | ((uint)o[1]<<16); v.y = o[2] | ((uint)o[3]<<16);
            v.z = o[4] | ((uint)o[5]<<16); v.w = o[6] | ((uint)o[7]<<16);
            *reinterpret_cast<uint4*>(dst + (((size_t)bb*NHEADS + hn)*P + p0 + pl)*32 + cs) = v;
        }
    }
}

// ---------------------------------------------------------------------------
// pack_w7: all 7 weight tensors fp32 -> bf16 in ONE launch (y selects pair)
// ---------------------------------------------------------------------------
__global__ __launch_bounds__(256) void pack_w7(
    const float* __restrict__ s0, const float* __restrict__ s1,
    const float* __restrict__ s2, const float* __restrict__ s3,
    const float* __restrict__ s4, const float* __restrict__ s5,
    const float* __restrict__ s6,
    ushort* __restrict__ d0, ushort* __restrict__ d1, ushort* __restrict__ d2,
    ushort* __restrict__ d3, ushort* __restrict__ d4, ushort* __restrict__ d5,
    ushort* __restrict__ d6, int n4)
{
    const float* src; ushort* dst;
    switch (blockIdx.y) {
        case 0: src = s0; dst = d0; break;
        case 1: src = s1; dst = d1; break;
        case 2: src = s2; dst = d2; break;
        case 3: src = s3; dst = d3; break;
        case 4: src = s4; dst = d4; break;
        case 5: src = s5; dst = d5; break;
        default: src = s6; dst = d6; break;
    }
    for (size_t i = (size_t)blockIdx.x * 256 + threadIdx.x; i < (size_t)n4;
         i += (size_t)gridDim.x * 256) {
        const float4 v = *reinterpret_cast<const float4*>(src + i*4);
        uint2 o;
        o.x = f2bf(v.x) | ((uint)f2bf(v.y) << 16);
        o.y = f2bf(v.z) | ((uint)f2bf(v.w) << 16);
        *reinterpret_cast<uint2*>(dst + i*4) = o;
    }
}

// ---------------------------------------------------------------------------
// proj_qkv6: demo + obs Q/K/V projections in ONE launch.
// blockIdx.x = b*50 + pt; pt<13 -> demo half (ncols=DPOS, pOff=0),
// else obs half (pt-13, ncols=OPOS, pOff=DPOS). z picks Q/K/V.
// Q (z==0) -> packed-T bf16, scaled by QS; K (z==1) -> packed-T bf16;
// V (z==2) -> natural bf16.
// ---------------------------------------------------------------------------
__global__ __launch_bounds__(256) void proj_qkv6(
    const ushort* __restrict__ XPK, float QS,
    const ushort* __restrict__ dQw, const ushort* __restrict__ dKw, const ushort* __restrict__ dVw,
    const ushort* __restrict__ oQw, const ushort* __restrict__ oKw, const ushort* __restrict__ oVw,
    ushort* __restrict__ QdP, ushort* __restrict__ KdP, ushort* __restrict__ VdemoP,
    ushort* __restrict__ QoP, ushort* __restrict__ KoP, ushort* __restrict__ VoP)
{
    const int b      = blockIdx.x / 50;
    const int pt_all = blockIdx.x % 50;
    const bool demo  = (pt_all < 13);
    const int pt     = demo ? pt_all : pt_all - 13;
    const int ncols  = demo ? DPOS : OPOS;
    const int pOff   = demo ? 0 : DPOS;
    const int fbase  = blockIdx.y * 64;
    const int z = blockIdx.z;
    const ushort* W  = demo ? (z == 0 ? dQw : z == 1 ? dKw : dVw)
                            : (z == 0 ? oQw : z == 1 ? oKw : oVw);
    ushort* O        = demo ? (z == 0 ? QdP : z == 1 ? KdP : VdemoP)
                            : (z == 0 ? QoP : z == 1 ? KoP : VoP);
    const int variant = (z == 2) ? 1 : 0;
    const float sc    = (z == 0) ? QS : 1.f;

    const int tid = threadIdx.x, lane = tid & 63, w = tid >> 6;
    const int l15 = lane & 15, grp = lane >> 4;

    __shared__ float Cf[64][68];

    f32x4 acc[4];
    #pragma unroll
    for (int nt = 0; nt < 4; ++nt) acc[nt] = (f32x4){0.f, 0.f, 0.f, 0.f};

    const ushort* Wrow = W + (size_t)(fbase + w*16 + l15) * CC;
    int prow[4];
    #pragma unroll
    for (int nt = 0; nt < 4; ++nt) {
        const int p = pt*64 + nt*16 + l15;
        prow[nt] = (p < ncols) ? p : (ncols - 1);   // clamp: dup rows discarded
    }
    const size_t xb = (size_t)b * 8;

    #pragma unroll
    for (int kc = 0; kc < 8; ++kc) {
        const s8v aW = *reinterpret_cast<const s8v*>(Wrow + kc*32 + grp*8);
        #pragma unroll
        for (int nt = 0; nt < 4; ++nt) {
            const s8v bX = *reinterpret_cast<const s8v*>(
                XPK + ((xb + kc)*XROW + pOff + prow[nt])*32 + grp*8);
            acc[nt] = __builtin_amdgcn_mfma_f32_16x16x32_bf16(aW, bX, acc[nt], 0, 0, 0);
        }
    }
    #pragma unroll
    for (int nt = 0; nt < 4; ++nt)
        #pragma unroll
        for (int r = 0; r < 4; ++r)
            Cf[w*16 + grp*4 + r][nt*16 + l15] = acc[nt][r] * sc;
    __syncthreads();

    if (variant == 0) {
        const int p_l = tid >> 2, c8 = (tid & 3) * 8;
        const int opos = pt*64 + p_l;
        if (opos < ncols) {
            #pragma unroll
            for (int hq = 0; hq < 2; ++hq) {
                ushort e[8];
                #pragma unroll
                for (int j = 0; j < 8; ++j) e[j] = f2bf(Cf[hq*32 + c8 + j][p_l]);
                uint4 v;
                v.x = e[0] | ((uint)e[1]<<16); v.y = e[2] | ((uint)e[3]<<16);
                v.z = e[4] | ((uint)e[5]<<16); v.w = e[6] | ((uint)e[7]<<16);
                *reinterpret_cast<uint4*>(
                    O + (((size_t)b*NHEADS + (fbase >> 5) + hq)*ncols + opos)*32 + c8) = v;
            }
        }
    } else {
        #pragma unroll
        for (int pass = 0; pass < 2; ++pass) {
            const int idx = pass*256 + tid;
            const int f_l = idx >> 3, u = idx & 7;
            const int p0 = pt*64 + u*8;
            if (p0 < ncols) {
                ushort e[8];
                #pragma unroll
                for (int j = 0; j < 8; ++j) e[j] = f2bf(Cf[f_l][u*8 + j]);
                uint4 v;
                v.x = e[0] | ((uint)e[1]<<16); v.y = e[2] | ((uint)e[3]<<16);
                v.z = e[4] | ((uint)e[5]<<16); v.w = e[6] | ((uint)e[7]<<16);
                *reinterpret_cast<uint4*>(
                    O + ((size_t)b*CC + fbase + f_l)*ncols + p0) = v;
            }
        }
    }
}

// ---------------------------------------------------------------------------
// proj_out: out-projection (K=256 over mergedP) with fused residual+ReLU:
//   v = resid_obs + relu(W . merged)
// ---------------------------------------------------------------------------
__global__ __launch_bounds__(256) void proj_out(
    const ushort* __restrict__ XPK,
    const ushort* __restrict__ W_,
    float* __restrict__ O, const float* __restrict__ resid)
{
    const int ptiles = 37;
    const int b  = blockIdx.x / ptiles;
    const int pt = blockIdx.x % ptiles;
    const int fbase = blockIdx.y * 64;

    const int tid = threadIdx.x, lane = tid & 63, w = tid >> 6;
    const int l15 = lane & 15, grp = lane >> 4;

    __shared__ float Cf[64][68];

    f32x4 acc[4];
    #pragma unroll
    for (int nt = 0; nt < 4; ++nt) acc[nt] = (f32x4){0.f, 0.f, 0.f, 0.f};

    const ushort* Wrow = W_ + (size_t)(fbase + w*16 + l15) * CC;
    int prow[4];
    #pragma unroll
    for (int nt = 0; nt < 4; ++nt) {
        const int p = pt*64 + nt*16 + l15;
        prow[nt] = (p < OPOS) ? p : (OPOS - 1);
    }
    const size_t xb = (size_t)b * 8;

    #pragma unroll
    for (int kc = 0; kc < 8; ++kc) {
        const s8v aW = *reinterpret_cast<const s8v*>(Wrow + kc*32 + grp*8);
        #pragma unroll
        for (int nt = 0; nt < 4; ++nt) {
            const s8v bX = *reinterpret_cast<const s8v*>(
                XPK + ((xb + kc)*OPOS + prow[nt])*32 + grp*8);
            acc[nt] = __builtin_amdgcn_mfma_f32_16x16x32_bf16(aW, bX, acc[nt], 0, 0, 0);
        }
    }
    #pragma unroll
    for (int nt = 0; nt < 4; ++nt)
        #pragma unroll
        for (int r = 0; r < 4; ++r)
            Cf[w*16 + grp*4 + r][nt*16 + l15] = acc[nt][r];
    __syncthreads();

    #pragma unroll
    for (int pass = 0; pass < 2; ++pass) {
        const int idx = pass*256 + tid;
        const int f_l = idx >> 3, u = idx & 7;
        const int p0 = pt*64 + u*8;
        if (p0 < OPOS) {
            const float* rp = resid + ((size_t)b*CC + fbase + f_l)*XROW + DPOS + p0;
            const float4 r0 = *reinterpret_cast<const float4*>(rp);
            const float4 r1 = *reinterpret_cast<const float4*>(rp + 4);
            float* dp = O + ((size_t)b*CC + fbase + f_l)*OPOS + p0;
            const float4 o0 = make_float4(
                r0.x + fmaxf(Cf[f_l][u*8+0], 0.f), r0.y + fmaxf(Cf[f_l][u*8+1], 0.f),
                r0.z + fmaxf(Cf[f_l][u*8+2], 0.f), r0.w + fmaxf(Cf[f_l][u*8+3], 0.f));
            const float4 o1 = make_float4(
                r1.x + fmaxf(Cf[f_l][u*8+4], 0.f), r1.y + fmaxf(Cf[f_l][u*8+5], 0.f),
                r1.z + fmaxf(Cf[f_l][u*8+6], 0.f), r1.w + fmaxf(Cf[f_l][u*8+7], 0.f));
            *reinterpret_cast<float4*>(dp)     = o0;
            *reinterpret_cast<float4*>(dp + 4) = o1;
        }
    }
}

// ---------------------------------------------------------------------------
// Demo attention — bf16 MFMA, 512 threads, NO-MAX softmax, barrier-free,
// flat loop with register prefetch. Q pre-scaled log2(e)/16 -> raw exp2.
// ---------------------------------------------------------------------------
__global__ __launch_bounds__(512) void demo_attn_mfma(
    const ushort* __restrict__ QdP, const ushort* __restrict__ KdP,
    const ushort* __restrict__ VdP, ushort* __restrict__ dvattP)
{
    const int ib = blockIdx.x, hn = blockIdx.y, bb = blockIdx.z;
    const int tid = threadIdx.x;
    const int g   = tid >> 8;          // j-half
    const int gt  = tid & 255;
    const int lane = tid & 63;
    const int w    = (tid >> 6) & 3;   // i-quarter
    const int l15 = lane & 15, grp = lane >> 4;

    __shared__ float mrg[2304];                       // Lb[256] Ob[2048]
    __shared__ __align__(16) ushort OutS[32*72];

    const size_t hBase = ((size_t)bb*NHEADS + hn) * DPOS;
    const size_t vRow0 = ((size_t)bb*CC + hn*CH) * DPOS;

    const int i_glob = ib*64 + w*16 + l15;
    const s8v bK = *reinterpret_cast<const s8v*>(KdP + (hBase + i_glob)*32 + grp*8);

    f32x4 accO[2] = {{0.f,0.f,0.f,0.f}, {0.f,0.f,0.f,0.f}};
    float l_run = 0.f;

    const int chBase = g ? 7 : 0;
    const int iters  = g ? 21 : 28;

    auto qAddr = [&](int it) -> const ushort* {
        const int ch = chBase + (it >> 2), jt = it & 3;
        return QdP + (hBase + ch*64 + jt*16 + l15)*32 + grp*8;
    };
    auto vAddr = [&](int it, int ct) -> const ushort* {
        const int ch = chBase + (it >> 2), jt = it & 3;
        return VdP + vRow0 + (size_t)(ct*16 + l15)*DPOS + ch*64 + jt*16 + grp*4;
    };

    s8v curQ  = *reinterpret_cast<const s8v*>(qAddr(0));
    s4v curV0 = *reinterpret_cast<const s4v*>(vAddr(0, 0));
    s4v curV1 = *reinterpret_cast<const s4v*>(vAddr(0, 1));

    for (int it = 0; it < iters; ++it) {
        s8v nQ; s4v nV0, nV1;
        if (it + 1 < iters) {
            nQ  = *reinterpret_cast<const s8v*>(qAddr(it + 1));
            nV0 = *reinterpret_cast<const s4v*>(vAddr(it + 1, 0));
            nV1 = *reinterpret_cast<const s4v*>(vAddr(it + 1, 1));
        }
        const f32x4 z = {0.f,0.f,0.f,0.f};
        const f32x4 st = __builtin_amdgcn_mfma_f32_16x16x32_bf16(curQ, bK, z, 0, 0, 0);
        const float e0 = fexp2(st[0]), e1 = fexp2(st[1]);
        const float e2 = fexp2(st[2]), e3 = fexp2(st[3]);
        l_run += (e0 + e1) + (e2 + e3);
        s4v pf4;
        pf4[0] = bfr(e0); pf4[1] = bfr(e1); pf4[2] = bfr(e2); pf4[3] = bfr(e3);
        accO[0] = mfma_pv(curV0, pf4, accO[0]);
        accO[1] = mfma_pv(curV1, pf4, accO[1]);
        curQ = nQ; curV0 = nV0; curV1 = nV1;
    }
    l_run += __shfl_xor(l_run, 16);
    l_run += __shfl_xor(l_run, 32);

    float* Lb = mrg;          // [256]
    float* Ob = mrg + 256;    // [256][8]
    if (g == 1) {
        Lb[w*64 + lane] = l_run;
        #pragma unroll
        for (int ct = 0; ct < 2; ++ct)
            #pragma unroll
            for (int r = 0; r < 4; ++r)
                Ob[(w*64 + lane)*8 + ct*4 + r] = accO[ct][r];
    }
    __syncthreads();
    if (g == 0) {
        const float linv = 1.f / (l_run + Lb[w*64 + lane]);
        #pragma unroll
        for (int ct = 0; ct < 2; ++ct)
            #pragma unroll
            for (int r = 0; r < 4; ++r) {
                const float o = (accO[ct][r] + Ob[(w*64 + lane)*8 + ct*4 + r]) * linv;
                OutS[(ct*16 + grp*4 + r)*72 + w*16 + l15] = f2bf(o);
            }
    }
    __syncthreads();
    if (g == 0) {
        const int c = gt >> 3, sg = gt & 7;
        const int col = ib*64 + sg*8;
        if (col < DPOS) {
            const uint4 v = *reinterpret_cast<const uint4*>(&OutS[c*72 + sg*8]);
            *reinterpret_cast<uint4*>(dvattP + vRow0 + (size_t)c*DPOS + col) = v;
        }
    }
}

// ---------------------------------------------------------------------------
// Obs attention per (b, t, n) — round-11 structure + normalizer FOLDED INTO
// THE V FRAGMENT: instead of scaling 52 P registers by 1/l (on the chain),
// scale the 4 V values per fragment (V[c,p]/l_p) — algebraically identical,
// 12 ops instead of 52, and a shorter dependency chain. is[r] is row-uniform
// after the DPP allreduce and indexes exactly the PV A-fragment k-slot.
// ---------------------------------------------------------------------------
__global__ __launch_bounds__(512) void obs_attn_mfma(
    const ushort* __restrict__ KdP, const ushort* __restrict__ KoP,
    const ushort* __restrict__ QP,  const ushort* __restrict__ VdP,
    const ushort* __restrict__ VoP, ushort* __restrict__ mergedP)
{
    const int tt = blockIdx.x, hn = blockIdx.y, bb = blockIdx.z;
    __shared__ __align__(16) ushort smem_u[27136];   // QT[208][40] ∪ Ored[2][32][212]f32
    ushort* QT = smem_u;

    const int tid  = threadIdx.x;
    const int g    = tid >> 8;
    const int lane = tid & 63;
    const int w    = (tid >> 6) & 3;
    const int l15  = lane & 15, grp = lane >> 4;

    const size_t kdBase = ((size_t)bb*NHEADS + hn) * DPOS * 32;
    const size_t koBase = ((size_t)bb*NHEADS + hn) * OPOS * 32 + (size_t)tt*HW*32;
    const size_t vdRow0 = ((size_t)bb*CC + hn*CH) * DPOS;
    const size_t voRow0 = ((size_t)bb*CC + hn*CH) * OPOS + (size_t)tt*HW;

    auto loadK = [&](int p0) -> s8v {
        const int pk = p0 + l15;
        s8v v = {0,0,0,0,0,0,0,0};
        if (pk < NPOS) {
            const ushort* kp = (pk < DPOS)
                ? KdP + kdBase + (size_t)pk*32
                : KoP + koBase + (size_t)(pk - DPOS)*32;
            v = *reinterpret_cast<const s8v*>(kp + grp*8);
        }
        return v;
    };
    auto loadV = [&](int ct, int p0) -> s4v {
        const int c  = ct*16 + l15;
        const int pv = p0 + grp*4;
        s4v v = {0,0,0,0};
        if (pv < NPOS) {
            const ushort* vp = (pv < DPOS)
                ? VdP + vdRow0 + (size_t)c*DPOS + pv
                : VoP + voRow0 + (size_t)c*OPOS + (pv - DPOS);
            v = *reinterpret_cast<const s4v*>(vp);
        }
        return v;
    };

    // stage Q once (rows >= 196 zero)
    for (int idx = tid; idx < 832; idx += 512) {
        const int r = idx >> 2, sg = idx & 3;
        uint4 v = {0,0,0,0};
        if (r < HW) v = *reinterpret_cast<const uint4*>(QP + koBase + (size_t)r*32 + sg*8);
        *reinterpret_cast<uint4*>(&QT[r*40 + sg*8]) = v;
    }

    f32x4 accO[2][13];
    #pragma unroll
    for (int ct = 0; ct < 2; ++ct)
        #pragma unroll
        for (int qt = 0; qt < 13; ++qt)
            accO[ct][qt] = (f32x4){0.f, 0.f, 0.f, 0.f};

    const int pw = (g*4 + w) * 128;
    s8v curK  = loadK(pw);
    s4v curV0 = loadV(0, pw);
    s4v curV1 = loadV(1, pw);
    __syncthreads();

    for (int s = 0; s < 8; ++s) {
        s8v nK = {0,0,0,0,0,0,0,0};
        s4v nV0 = {0,0,0,0}, nV1 = {0,0,0,0};
        if (s < 7) {
            const int np = pw + (s+1)*16;
            nK  = loadK(np);
            nV0 = loadV(0, np);
            nV1 = loadV(1, np);
        }
        f32x4 ss[13];
        #pragma unroll
        for (int qt = 0; qt < 13; ++qt) {
            const s8v bQ = *reinterpret_cast<const s8v*>(&QT[(qt*16 + l15)*40 + grp*8]);
            const f32x4 z = {0.f, 0.f, 0.f, 0.f};
            ss[qt] = __builtin_amdgcn_mfma_f32_16x16x32_bf16(curK, bQ, z, 0, 0, 0);
        }
        // ---- no-max softmax: exp2 + per-row sum; P left UNNORMALIZED ----
        float isr[4];
        #pragma unroll
        for (int r = 0; r < 4; ++r) {
            #pragma unroll
            for (int qt = 0; qt < 13; ++qt) ss[qt][r] = fexp2(ss[qt][r]);
            if (l15 >= 4) ss[12][r] = 0.f;   // q >= 196 pad (needed for the sum)
            float sum = ((((ss[0][r]+ss[1][r]) + (ss[2][r]+ss[3][r]))
                        + ((ss[4][r]+ss[5][r]) + (ss[6][r]+ss[7][r])))
                        + (((ss[8][r]+ss[9][r]) + (ss[10][r]+ss[11][r])) + ss[12][r]));
            sum = row16_sum(sum);
            isr[r] = fast_rcp(sum);
        }
        s4v pf[13];
        #pragma unroll
        for (int qt = 0; qt < 13; ++qt) {
            s4v p4;
            #pragma unroll
            for (int r = 0; r < 4; ++r) p4[r] = bfr(ss[qt][r]);
            pf[qt] = p4;
        }
        // ---- scale V fragments by 1/l_p (k-slot r == softmax row r) ----
        s4v v0s, v1s;
        #pragma unroll
        for (int r = 0; r < 4; ++r) {
            v0s[r] = bfr(bf2f(curV0[r]) * isr[r]);
            v1s[r] = bfr(bf2f(curV1[r]) * isr[r]);
        }
        #pragma unroll
        for (int qt = 0; qt < 13; ++qt)
            accO[0][qt] = mfma_pv(v0s, pf[qt], accO[0][qt]);
        #pragma unroll
        for (int qt = 0; qt < 13; ++qt)
            accO[1][qt] = mfma_pv(v1s, pf[qt], accO[1][qt]);

        curK = nK; curV0 = nV0; curV1 = nV1;
    }
    __syncthreads();

    // ---- per-group 4-wave reduction into Ored[g] ----
    float* OredF = reinterpret_cast<float*>(smem_u);   // [2][32][212]
    float* Og = OredF + g * 6784;
    for (int wv = 0; wv < 4; ++wv) {
        if (w == wv) {
            #pragma unroll
            for (int ct = 0; ct < 2; ++ct)
                #pragma unroll
                for (int qt = 0; qt < 13; ++qt)
                    #pragma unroll
                    for (int r = 0; r < 4; ++r) {
                        const int c = ct*16 + grp*4 + r;
                        const int q = qt*16 + l15;
                        if (wv == 0) Og[c*212 + q]  = accO[ct][qt][r];
                        else         Og[c*212 + q] += accO[ct][qt][r];
                    }
        }
        __syncthreads();
    }
    for (int idx = tid; idx < HW*4; idx += 512) {
        const int q = idx >> 2, c8 = (idx & 3) * 8;
        ushort e[8];
        #pragma unroll
        for (int j = 0; j < 8; ++j) {
            const int c = c8 + j;
            e[j] = f2bf(OredF[c*212 + q] + OredF[6784 + c*212 + q]);
        }
        uint4 v;
        v.x = e[0] | ((uint)e[1]<<16); v.y = e[2] | ((uint)e[3]<<16);
        v.z = e[4] | ((uint)e[5]<<16); v.w = e[6] | ((uint)e[7]<<16);
        *reinterpret_cast<uint4*>(
            mergedP + (((size_t)bb*NHEADS + hn)*OPOS + (size_t)tt*HW + q)*32 + c8) = v;
    }
}

// ---------------------------------------------------------------------------
// bn_stats: per-channel mean/rstd over cat(xin_demo, v). One block/channel.
// ---------------------------------------------------------------------------
__global__ __launch_bounds__(256) void bn_stats(
    const float* __restrict__ xin, const float* __restrict__ v,
    float2* __restrict__ stats)
{
    const int c = blockIdx.x;
    const int tid = threadIdx.x;
    float sum = 0.f, sumsq = 0.f;
    for (int idx = tid; idx < BB*(DPOS/4); idx += 256) {
        const int b = idx / (DPOS/4), pos = idx % (DPOS/4);
        const float4 x4 = *reinterpret_cast<const float4*>(
            &xin[((size_t)b*CC + c) * XROW + pos*4]);
        sum   += x4.x + x4.y + x4.z + x4.w;
        sumsq += x4.x*x4.x + x4.y*x4.y + x4.z*x4.z + x4.w*x4.w;
    }
    for (int idx = tid; idx < BB*(OPOS/4); idx += 256) {
        const int b = idx / (OPOS/4), pos = idx % (OPOS/4);
        const float4 v4 = *reinterpret_cast<const float4*>(
            &v[((size_t)b*CC + c) * OPOS + pos*4]);
        sum   += v4.x + v4.y + v4.z + v4.w;
        sumsq += v4.x*v4.x + v4.y*v4.y + v4.z*v4.z + v4.w*v4.w;
    }
    #pragma unroll
    for (int off = 32; off > 0; off >>= 1) {
        sum   += __shfl_xor(sum, off);
        sumsq += __shfl_xor(sumsq, off);
    }
    __shared__ float ssum[4], ssq[4];
    const int lane = tid & 63, w = tid >> 6;
    if (lane == 0) { ssum[w] = sum; ssq[w] = sumsq; }
    __syncthreads();
    if (tid == 0) {
        const float s  = ssum[0] + ssum[1] + ssum[2] + ssum[3];
        const float sq = ssq[0] + ssq[1] + ssq[2] + ssq[3];
        const float mean = s / 12544.f;
        const float var  = sq / 12544.f - mean * mean;
        stats[c] = make_float2(mean, rsqrtf(var + 1e-5f));
    }
}

// ---------------------------------------------------------------------------
// bn_apply: normalize cat(xin_demo, v) -> xout fp32, optionally emit next
// layer's packed-T bf16 XP via LDS transpose.
// ---------------------------------------------------------------------------
__global__ __launch_bounds__(256) void bn_apply(
    const float* __restrict__ xin, const float* __restrict__ v,
    const float2* __restrict__ stats,
    const float* __restrict__ gamma, const float* __restrict__ beta,
    float* __restrict__ xout, ushort* __restrict__ XPdst)
{
    const int hn = blockIdx.y, bb = blockIdx.z;
    const int p0 = blockIdx.x * 64;
    __shared__ float L[32][73];
    const int tid = threadIdx.x;
    const int c  = tid >> 3, sg = tid & 7;
    const int cg = hn*CH + c;
    const float2 st = stats[cg];
    const float gi  = gamma[cg] * st.y;
    const float bt  = beta[cg];
    const int p = p0 + sg*8;

    float vals[8];
    if (p + 7 < DPOS) {
        const float* s = xin + ((size_t)bb*CC + cg) * XROW + p;
        const float4 a = *reinterpret_cast<const float4*>(s);
        const float4 b2 = *reinterpret_cast<const float4*>(s + 4);
        vals[0]=a.x; vals[1]=a.y; vals[2]=a.z; vals[3]=a.w;
        vals[4]=b2.x; vals[5]=b2.y; vals[6]=b2.z; vals[7]=b2.w;
    } else if (p >= DPOS) {
        const float* s = v + ((size_t)bb*CC + cg) * OPOS + (p - DPOS);
        const float4 a = *reinterpret_cast<const float4*>(s);
        const float4 b2 = *reinterpret_cast<const float4*>(s + 4);
        vals[0]=a.x; vals[1]=a.y; vals[2]=a.z; vals[3]=a.w;
        vals[4]=b2.x; vals[5]=b2.y; vals[6]=b2.z; vals[7]=b2.w;
    } else {
        #pragma unroll
        for (int j = 0; j < 8; ++j) {
            const int pp = p + j;
            vals[j] = (pp < DPOS)
                ? xin[((size_t)bb*CC + cg) * XROW + pp]
                : v[((size_t)bb*CC + cg) * OPOS + (pp - DPOS)];
        }
    }
    float4 o0, o1;
    o0.x = (vals[0]-st.x)*gi + bt; o0.y = (vals[1]-st.x)*gi + bt;
    o0.z = (vals[2]-st.x)*gi + bt; o0.w = (vals[3]-st.x)*gi + bt;
    o1.x = (vals[4]-st.x)*gi + bt; o1.y = (vals[5]-st.x)*gi + bt;
    o1.z = (vals[6]-st.x)*gi + bt; o1.w = (vals[7]-st.x)*gi + bt;
    {
        float* dp = xout + ((size_t)bb*CC + cg) * XROW + p;
        *reinterpret_cast<float4*>(dp)     = o0;
        *reinterpret_cast<float4*>(dp + 4) = o1;
    }
    if (XPdst) {
        L[c][sg*8+0]=o0.x; L[c][sg*8+1]=o0.y; L[c][sg*8+2]=o0.z; L[c][sg*8+3]=o0.w;
        L[c][sg*8+4]=o1.x; L[c][sg*8+5]=o1.y; L[c][sg*8+6]=o1.z; L[c][sg*8+7]=o1.w;
        __syncthreads();
        const int pl = tid >> 2, cs = (tid & 3) * 8;
        ushort e[8];
        #pragma unroll
        for (int j = 0; j < 8; j++) e[j] = f2bf(L[cs+j][pl]);
        uint4 vv;
        vv.x = e[0] | ((uint)e[1]<<16); vv.y = e[2] | ((uint)e[3]<<16);
        vv.z = e[4] | ((uint)e[5]<<16); vv.w = e[6] | ((uint)e[7]<<16);
        *reinterpret_cast<uint4*>(
            XPdst + (((size_t)bb*NHEADS + hn)*XROW + p0 + pl)*32 + cs) = vv;
    }
}

// ---------------------------------------------------------------------------
extern "C" void kernel_launch(void* const* d_in, const int* in_sizes, int n_in,
                              void* d_out, int out_size, void* d_ws, size_t ws_size,
                              hipStream_t stream)
{
    const float* x   = (const float*)d_in[0];
    const float* dqw = (const float*)d_in[1];
    const float* dkw = (const float*)d_in[2];
    const float* dvw = (const float*)d_in[3];
    const float* oqw = (const float*)d_in[4];
    const float* okw = (const float*)d_in[5];
    const float* ovw = (const float*)d_in[6];
    const float* oow = (const float*)d_in[7];
    const float* gam = (const float*)d_in[8];
    const float* bet = (const float*)d_in[9];

    const size_t XN = (size_t)BB * CC * TT * HW;   // 3,211,264
    const size_t DN = (size_t)BB * CC * DPOS;      //   802,816
    const size_t ON = (size_t)BB * CC * OPOS;      // 2,408,448
    const size_t WN = (size_t)3 * CC * CC;         //   196,608

    float*  xb0     = (float*)d_ws;
    float*  xb1     = xb0 + XN;
    float*  obsout  = xb1 + XN;                   // holds v = obs_new
    ushort* XP      = (ushort*)(obsout + ON);     // [b][8][3136][32]
    ushort* QdP     = XP + XN;
    ushort* KdP     = QdP + DN;
    ushort* VdemoP  = KdP + DN;
    ushort* dvattP  = VdemoP + DN;
    ushort* QP      = dvattP + DN;
    ushort* KoP     = QP + ON;
    ushort* VoP     = KoP + ON;
    ushort* mergedP = VoP + ON;
    ushort* wpk     = mergedP + ON;
    ushort* dqwb = wpk;          ushort* dkwb = wpk + WN;   ushort* dvwb = wpk + 2*WN;
    ushort* oqwb = wpk + 3*WN;   ushort* okwb = wpk + 4*WN; ushort* ovwb = wpk + 5*WN;
    ushort* oowb = wpk + 6*WN;
    float2* statsB = (float2*)(wpk + 7*WN);       // 256 float2

    const dim3 blk(256);
    const dim3 blk2(512);
    const float QS = 0.0625f * 1.44269504f;   // (1/sqrt(C)) * log2(e) -> raw exp2 in attn

    pack_w7<<<dim3(192, 7), blk, 0, stream>>>(
        dqw, dkw, dvw, oqw, okw, ovw, oow,
        dqwb, dkwb, dvwb, oqwb, okwb, ovwb, oowb, (int)(WN/4));

    // initial input pack (layers 1-2 get XP from bn_apply)
    pack_T<<<dim3(49, 8, BB), blk, 0, stream>>>(x, XP, XROW);

    for (int i = 0; i < 3; i++) {
        const float* xin  = (i == 0) ? x : (i == 1 ? xb0 : xb1);
        float*       xout = (i == 2) ? (float*)d_out : (i == 0 ? xb0 : xb1);
        const size_t wB = (size_t)i * CC * CC;

        // 1: demo + obs Q/K/V projections in ONE launch (2400 blocks)
        proj_qkv6<<<dim3(BB*50, 4, 3), blk, 0, stream>>>(
            XP, QS,
            dqwb + wB, dkwb + wB, dvwb + wB,
            oqwb + wB, okwb + wB, ovwb + wB,
            QdP, KdP, VdemoP, QP, KoP, VoP);

        // 2: demo attention
        demo_attn_mfma<<<dim3(13, NHEADS, BB), blk2, 0, stream>>>(
            QdP, KdP, VdemoP, dvattP);

        // 3: obs attention -> mergedP
        obs_attn_mfma<<<dim3(OBS_T, NHEADS, BB), blk2, 0, stream>>>(
            KdP, KoP, QP, dvattP, VoP, mergedP);

        // 4: output projection, fused residual+ReLU -> v (fp32)
        proj_out<<<dim3(BB*37, 4), blk, 0, stream>>>(
            mergedP, oowb + wB, obsout, xin);

        // 5: BN stats
        bn_stats<<<dim3(CC), blk, 0, stream>>>(xin, obsout, statsB);

        // 6: BN apply (+ pack next layer's XP; final layer skips XP)
        bn_apply<<<dim3(49, 8, BB), blk, 0, stream>>>(
            xin, obsout, statsB, gam + i*CC, bet + i*CC, xout,
            (i < 2) ? XP : nullptr);
    }
}